// Round 5
// baseline (578.664 us; speedup 1.0000x reference)
//
#include <hip/hip_runtime.h>
#include <math.h>

#define BB 2
#define NN 16000
#define EE 160000
#define KK 128
#define CC 64
#define LL 3

typedef __attribute__((ext_vector_type(8))) short bf16x8;
typedef __attribute__((ext_vector_type(4))) float f32x4;

__device__ __forceinline__ float gelu_f(float x){
    float x3 = x * x * x;
    return 0.5f * x * (1.f + tanhf(0.7978845608028654f * (x + 0.044715f * x3)));
}
__device__ __forceinline__ ushort f2bf(float f){
    uint u = __float_as_uint(f);
    u += 0x7fff + ((u >> 16) & 1);
    return (ushort)(u >> 16);
}
__device__ __forceinline__ float bf2f(ushort h){ return __uint_as_float(((uint)h) << 16); }
__device__ __forceinline__ void fsplit(float v, ushort &hi, ushort &lo){
    hi = f2bf(v);
    lo = f2bf(v - bf2f(hi));
}
__device__ __forceinline__ uint pk2(ushort a, ushort b){ return (uint)a | ((uint)b << 16); }

// ---------------------------------------------------------------- shared epilogue: LDS h-tile [128x][68] -> all h formats
__device__ __forceinline__ void write_h_outputs(
    const float* ot, const float* nws, int b, int s, int x0, int t, int doAux,
    float* __restrict__ hx, ushort* __restrict__ hxh, ushort* __restrict__ hxl,
    ushort* __restrict__ hwh, ushort* __restrict__ hwl, float* __restrict__ part0){
    {
        int xl = t >> 1, half = t & 1;
        size_t gb = ((size_t)b*NN + x0 + xl)*64 + half*32;
        const float* row = &ot[xl*68 + half*32];
        #pragma unroll
        for (int j = 0; j < 8; j++){
            float4 v; v.x = row[j*4]; v.y = row[j*4+1]; v.z = row[j*4+2]; v.w = row[j*4+3];
            *(float4*)&hx[gb + j*4] = v;
        }
        if (doAux){
            #pragma unroll
            for (int q = 0; q < 4; q++){
                ushort h_[8], l_[8];
                #pragma unroll
                for (int j = 0; j < 8; j++) fsplit(row[q*8 + j], h_[j], l_[j]);
                uint4 vh, vl;
                vh.x = pk2(h_[0],h_[1]); vh.y = pk2(h_[2],h_[3]); vh.z = pk2(h_[4],h_[5]); vh.w = pk2(h_[6],h_[7]);
                vl.x = pk2(l_[0],l_[1]); vl.y = pk2(l_[2],l_[3]); vl.z = pk2(l_[4],l_[5]); vl.w = pk2(l_[6],l_[7]);
                *(uint4*)&hxh[gb + q*8] = vh;
                *(uint4*)&hxl[gb + q*8] = vl;
            }
        }
    }
    if (doAux){
        int i = t & 63, g = t >> 6;
        float a = 0.f;
        #pragma unroll
        for (int rep = 0; rep < 4; rep++){
            int xs = g*32 + rep*8;
            ushort h_[8], l_[8];
            #pragma unroll
            for (int j = 0; j < 8; j++){
                float v = ot[(xs + j)*68 + i] * nws[xs + j];
                a += v;
                fsplit(v, h_[j], l_[j]);
            }
            uint4 vh, vl;
            vh.x = pk2(h_[0],h_[1]); vh.y = pk2(h_[2],h_[3]); vh.z = pk2(h_[4],h_[5]); vh.w = pk2(h_[6],h_[7]);
            vl.x = pk2(l_[0],l_[1]); vl.y = pk2(l_[2],l_[3]); vl.z = pk2(l_[4],l_[5]); vl.w = pk2(l_[6],l_[7]);
            size_t wb = (size_t)(b*64 + i)*16000 + x0 + xs;
            *(uint4*)&hwh[wb] = vh;
            *(uint4*)&hwl[wb] = vl;
        }
        part0[((size_t)(b*125 + s)*4 + g)*64 + i] = a;
    }
}

// ---------------------------------------------------------------- roles for merged start kernel
__device__ void bases_role(
    int bid, char* smem,
    const float* __restrict__ nodes, const float* __restrict__ modes,
    const float* __restrict__ latent, const float* __restrict__ nw,
    ushort* __restrict__ cbh, ushort* __restrict__ cbl,
    ushort* __restrict__ sbh, ushort* __restrict__ sbl,
    ushort* __restrict__ wTh, ushort* __restrict__ wTl){
    int b = bid / 250, x0 = (bid % 250) * 64;
    int t = threadIdx.x;
    float* sm0 = (float*)smem;          // 128
    float* sm1 = sm0 + 128;             // 128
    float* nwv = sm1 + 128;             // 64
    uint* tc = (uint*)(nwv + 64);       // 64*65
    uint* ts = tc + 64*65;              // 64*65
    if (t < 128){
        float i0 = 0.5f + 1.5f / (1.f + expf(-latent[0]));
        float i1 = 0.5f + 1.5f / (1.f + expf(-latent[1]));
        sm0[t] = modes[t*2+0] * i0;
        sm1[t] = modes[t*2+1] * i1;
    }
    if (t < 64) nwv[t] = nw[b*NN + x0 + t];
    __syncthreads();
    int xloc = t & 63;
    float n0 = nodes[((size_t)b*NN + x0 + xloc)*2 + 0];
    float n1 = nodes[((size_t)b*NN + x0 + xloc)*2 + 1];
    for (int kh = 0; kh < 2; kh++){
        int kq = t >> 6;
        #pragma unroll
        for (int j = 0; j < 16; j++){
            int kl = kq*16 + j;
            int k = kh*64 + kl;
            float tmp = n0*sm0[k] + n1*sm1[k];
            float sv, cv; sincosf(tmp, &sv, &cv);
            ushort h_, l_;
            fsplit(cv, h_, l_); tc[xloc*65 + kl] = pk2(h_, l_);
            fsplit(sv, h_, l_); ts[xloc*65 + kl] = pk2(h_, l_);
        }
        __syncthreads();
        {   // write cb/sb x-major (lanes along k)
            int q = t >> 6;
            size_t base = ((size_t)b*NN + x0 + xloc)*128 + kh*64 + q*16;
            #pragma unroll
            for (int g2 = 0; g2 < 2; g2++){
                uint u0 = tc[xloc*65 + q*16 + g2*8 + 0], u1 = tc[xloc*65 + q*16 + g2*8 + 1];
                uint u2 = tc[xloc*65 + q*16 + g2*8 + 2], u3 = tc[xloc*65 + q*16 + g2*8 + 3];
                uint u4 = tc[xloc*65 + q*16 + g2*8 + 4], u5 = tc[xloc*65 + q*16 + g2*8 + 5];
                uint u6 = tc[xloc*65 + q*16 + g2*8 + 6], u7 = tc[xloc*65 + q*16 + g2*8 + 7];
                uint4 vh, vl;
                vh.x = pk2((ushort)u0,(ushort)u1); vh.y = pk2((ushort)u2,(ushort)u3);
                vh.z = pk2((ushort)u4,(ushort)u5); vh.w = pk2((ushort)u6,(ushort)u7);
                vl.x = pk2((ushort)(u0>>16),(ushort)(u1>>16)); vl.y = pk2((ushort)(u2>>16),(ushort)(u3>>16));
                vl.z = pk2((ushort)(u4>>16),(ushort)(u5>>16)); vl.w = pk2((ushort)(u6>>16),(ushort)(u7>>16));
                *(uint4*)&cbh[base + g2*8] = vh;
                *(uint4*)&cbl[base + g2*8] = vl;
                u0 = ts[xloc*65 + q*16 + g2*8 + 0]; u1 = ts[xloc*65 + q*16 + g2*8 + 1];
                u2 = ts[xloc*65 + q*16 + g2*8 + 2]; u3 = ts[xloc*65 + q*16 + g2*8 + 3];
                u4 = ts[xloc*65 + q*16 + g2*8 + 4]; u5 = ts[xloc*65 + q*16 + g2*8 + 5];
                u6 = ts[xloc*65 + q*16 + g2*8 + 6]; u7 = ts[xloc*65 + q*16 + g2*8 + 7];
                vh.x = pk2((ushort)u0,(ushort)u1); vh.y = pk2((ushort)u2,(ushort)u3);
                vh.z = pk2((ushort)u4,(ushort)u5); vh.w = pk2((ushort)u6,(ushort)u7);
                vl.x = pk2((ushort)(u0>>16),(ushort)(u1>>16)); vl.y = pk2((ushort)(u2>>16),(ushort)(u3>>16));
                vl.z = pk2((ushort)(u4>>16),(ushort)(u5>>16)); vl.w = pk2((ushort)(u6>>16),(ushort)(u7>>16));
                *(uint4*)&sbh[base + g2*8] = vh;
                *(uint4*)&sbl[base + g2*8] = vl;
            }
        }
        {   // write wT k-major weighted
            int k = t & 63, g = t >> 6;
            int kgc = kh*64 + k;
            int kgs = 128 + kh*64 + k;
            ushort hc[16], lc[16], hs[16], ls[16];
            #pragma unroll
            for (int j = 0; j < 16; j++){
                int xx = g*16 + j;
                float wgt = nwv[xx];
                uint uc = tc[xx*65 + k], us = ts[xx*65 + k];
                float vc = (bf2f((ushort)uc) + bf2f((ushort)(uc>>16))) * wgt;
                float vs = (bf2f((ushort)us) + bf2f((ushort)(us>>16))) * wgt;
                fsplit(vc, hc[j], lc[j]);
                fsplit(vs, hs[j], ls[j]);
            }
            size_t wbc = ((size_t)b*256 + kgc)*16000 + x0 + g*16;
            size_t wbs = ((size_t)b*256 + kgs)*16000 + x0 + g*16;
            uint4 v;
            v.x = pk2(hc[0],hc[1]); v.y = pk2(hc[2],hc[3]); v.z = pk2(hc[4],hc[5]); v.w = pk2(hc[6],hc[7]);
            *(uint4*)&wTh[wbc] = v;
            v.x = pk2(hc[8],hc[9]); v.y = pk2(hc[10],hc[11]); v.z = pk2(hc[12],hc[13]); v.w = pk2(hc[14],hc[15]);
            *(uint4*)&wTh[wbc + 8] = v;
            v.x = pk2(lc[0],lc[1]); v.y = pk2(lc[2],lc[3]); v.z = pk2(lc[4],lc[5]); v.w = pk2(lc[6],lc[7]);
            *(uint4*)&wTl[wbc] = v;
            v.x = pk2(lc[8],lc[9]); v.y = pk2(lc[10],lc[11]); v.z = pk2(lc[12],lc[13]); v.w = pk2(lc[14],lc[15]);
            *(uint4*)&wTl[wbc + 8] = v;
            v.x = pk2(hs[0],hs[1]); v.y = pk2(hs[2],hs[3]); v.z = pk2(hs[4],hs[5]); v.w = pk2(hs[6],hs[7]);
            *(uint4*)&wTh[wbs] = v;
            v.x = pk2(hs[8],hs[9]); v.y = pk2(hs[10],hs[11]); v.z = pk2(hs[12],hs[13]); v.w = pk2(hs[14],hs[15]);
            *(uint4*)&wTh[wbs + 8] = v;
            v.x = pk2(ls[0],ls[1]); v.y = pk2(ls[2],ls[3]); v.z = pk2(ls[4],ls[5]); v.w = pk2(ls[6],ls[7]);
            *(uint4*)&wTl[wbs] = v;
            v.x = pk2(ls[8],ls[9]); v.y = pk2(ls[10],ls[11]); v.z = pk2(ls[12],ls[13]); v.w = pk2(ls[14],ls[15]);
            *(uint4*)&wTl[wbs + 8] = v;
        }
        __syncthreads();
    }
}

__device__ void fc0_role(
    int bid, char* smem,
    const float* __restrict__ x, const float* __restrict__ W,
    const float* __restrict__ bb, const float* __restrict__ nw,
    float* __restrict__ hx, ushort* __restrict__ hxh, ushort* __restrict__ hxl,
    ushort* __restrict__ hwh, ushort* __restrict__ hwl, float* __restrict__ part0){
    int b = bid / 125, s = bid % 125;
    int x0 = s * 128;
    int t = threadIdx.x;
    float* ot  = (float*)smem;      // 128*68
    float* nws = ot + 128*68;       // 128
    float* Wf  = nws + 128;         // 192
    float* bf_ = Wf + 192;          // 64
    if (t < 192) Wf[t] = W[t];
    if (t < 64) bf_[t] = bb[t];
    if (t < 128) nws[t] = nw[b*NN + x0 + t];
    __syncthreads();
    {
        int xl = t >> 1, half = t & 1;
        float v0 = x[((size_t)b*NN + x0 + xl)*3 + 0];
        float v1 = x[((size_t)b*NN + x0 + xl)*3 + 1];
        float v2 = x[((size_t)b*NN + x0 + xl)*3 + 2];
        #pragma unroll
        for (int j = 0; j < 32; j++){
            int o = half*32 + j;
            ot[xl*68 + o] = Wf[o*3]*v0 + Wf[o*3+1]*v1 + Wf[o*3+2]*v2 + bf_[o];
        }
    }
    __syncthreads();
    write_h_outputs(ot, nws, b, s, x0, t, 1, hx, hxh, hxl, hwh, hwl, part0);
}

// S1: bases (500) | fc0 (250) | zero-cnt (125)
__global__ __launch_bounds__(256) void k_start(
    const float* __restrict__ nodes, const float* __restrict__ modes,
    const float* __restrict__ latent, const float* __restrict__ nw,
    const float* __restrict__ x, const float* __restrict__ fc0W,
    const float* __restrict__ fc0b,
    ushort* __restrict__ cbh, ushort* __restrict__ cbl,
    ushort* __restrict__ sbh, ushort* __restrict__ sbl,
    ushort* __restrict__ wTh, ushort* __restrict__ wTl,
    float* __restrict__ hx, ushort* __restrict__ hxh, ushort* __restrict__ hxl,
    ushort* __restrict__ hwh, ushort* __restrict__ hwl, float* __restrict__ part0,
    int* __restrict__ cnt){
    __shared__ __align__(16) char smem[36864];
    int bid = blockIdx.x;
    if (bid < BB*250){
        bases_role(bid, smem, nodes, modes, latent, nw, cbh, cbl, sbh, sbl, wTh, wTl);
    } else if (bid < BB*250 + BB*125){
        fc0_role(bid - BB*250, smem, x, fc0W, fc0b, nw, hx, hxh, hxl, hwh, hwl, part0);
    } else {
        int idx = (bid - (BB*250 + BB*125))*256 + threadIdx.x;   // 125*256 == BB*NN
        cnt[idx] = 0;
    }
}

// ---------------------------------------------------------------- CSR build
__global__ __launch_bounds__(256) void csr_hist(
    const int* __restrict__ edges, int* __restrict__ cnt){
    int idx = blockIdx.x * 256 + threadIdx.x;
    if (idx >= BB*EE) return;
    int b = idx / EE;
    int tgt = edges[(size_t)idx*2];
    atomicAdd(&cnt[b*NN + tgt], 1);
}

__global__ __launch_bounds__(1024) void csr_scan(
    const int* __restrict__ cnt, int* __restrict__ rowptr, int* __restrict__ cursor){
    int b = blockIdx.x;
    int t = threadIdx.x;
    __shared__ int lds[1024];
    int base = t * 16;
    int v[16];
    int run = 0;
    #pragma unroll
    for (int j = 0; j < 16; j++){
        int n = base + j;
        int c = (n < NN) ? cnt[b*NN + n] : 0;
        v[j] = run;
        run += c;
    }
    lds[t] = run;
    __syncthreads();
    for (int off = 1; off < 1024; off <<= 1){
        int xv = (t >= off) ? lds[t-off] : 0;
        __syncthreads();
        lds[t] += xv;
        __syncthreads();
    }
    int toff = lds[t] - run;  // exclusive
    #pragma unroll
    for (int j = 0; j < 16; j++){
        int n = base + j;
        if (n < NN){
            int p = toff + v[j];
            rowptr[b*(NN+1) + n] = p;
            cursor[b*NN + n] = p;
        }
    }
    if (t == 1023) rowptr[b*(NN+1) + NN] = lds[1023];
}

__global__ __launch_bounds__(256) void csr_fill(
    const int* __restrict__ edges, const float* __restrict__ egw,
    int* __restrict__ cursor, int* __restrict__ insrc, float2* __restrict__ inw){
    int idx = blockIdx.x * 256 + threadIdx.x;
    if (idx >= BB*EE) return;
    int b = idx / EE;
    int tgt = edges[(size_t)idx*2];
    int src = edges[(size_t)idx*2 + 1];
    int pos = atomicAdd(&cursor[b*NN + tgt], 1);
    insrc[(size_t)b*EE + pos] = src;
    const float2 wv = *(const float2*)&egw[(size_t)idx*2];
    inw[(size_t)b*EE + pos] = wv;
}

// ---------------------------------------------------------------- D1 roles
__device__ void fwd_role(
    int bid, char* smem,
    const ushort* __restrict__ hwH, const ushort* __restrict__ hwL,
    const ushort* __restrict__ wTH, const ushort* __restrict__ wTL,
    float* __restrict__ part){
    int b = bid / 250, s = bid % 250;
    int x0 = s * 64;
    int t = threadIdx.x, l = t & 63, w = t >> 6;
    ushort* Bh = (ushort*)smem;        // 128*64
    ushort* Bl = Bh + 128*64;
    f32x4 acc[16] = {};
    bf16x8 Ah[2], Al[2];
    int i = w*16 + (l & 15);
    #pragma unroll
    for (int ks = 0; ks < 2; ks++){
        size_t ab = (size_t)(b*64 + i)*16000 + x0 + ks*32 + ((l >> 4) * 8);
        Ah[ks] = *reinterpret_cast<const bf16x8*>(&hwH[ab]);
        Al[ks] = *reinterpret_cast<const bf16x8*>(&hwL[ab]);
    }
    for (int p = 0; p < 2; p++){
        if (p) __syncthreads();
        #pragma unroll
        for (int it = 0; it < 4; it++){
            int u = it*256 + t;
            int kloc = u >> 3, q = u & 7;
            size_t g = ((size_t)(b*256 + p*128 + kloc))*16000 + x0 + q*8;
            uint4 vh = *(const uint4*)&wTH[g];
            uint4 vl = *(const uint4*)&wTL[g];
            int ldsb = kloc*128 + ((q*16) ^ ((kloc & 7) << 4));
            *(uint4*)&Bh[ldsb >> 1] = vh;
            *(uint4*)&Bl[ldsb >> 1] = vl;
        }
        __syncthreads();
        #pragma unroll
        for (int kt = 0; kt < 8; kt++){
            int kcol = kt*16 + (l & 15);
            int ai = p*8 + kt;
            #pragma unroll
            for (int ks = 0; ks < 2; ks++){
                int boff = kcol*128 + (((ks*64) + ((l >> 4) * 16)) ^ ((kcol & 7) << 4));
                bf16x8 bh = *reinterpret_cast<const bf16x8*>(&Bh[boff >> 1]);
                bf16x8 bl = *reinterpret_cast<const bf16x8*>(&Bl[boff >> 1]);
                acc[ai] = __builtin_amdgcn_mfma_f32_16x16x32_bf16(Ah[ks], bh, acc[ai], 0, 0, 0);
                acc[ai] = __builtin_amdgcn_mfma_f32_16x16x32_bf16(Ah[ks], bl, acc[ai], 0, 0, 0);
                acc[ai] = __builtin_amdgcn_mfma_f32_16x16x32_bf16(Al[ks], bh, acc[ai], 0, 0, 0);
            }
        }
    }
    size_t pb = (size_t)(b*250 + s) * 64 * 256;
    #pragma unroll
    for (int nt = 0; nt < 16; nt++){
        #pragma unroll
        for (int r = 0; r < 4; r++){
            int irow = w*16 + (l >> 4)*4 + r;
            part[pb + (size_t)irow*256 + nt*16 + (l & 15)] = acc[nt][r];
        }
    }
}

__device__ void grad_role(
    int bid,
    const float* __restrict__ h, const int* __restrict__ rowptr,
    const int* __restrict__ insrc, const float2* __restrict__ inw,
    ushort* __restrict__ segh, ushort* __restrict__ segl){
    int b = bid / 2000, n0 = (bid % 2000) * 8;
    int w = threadIdx.x >> 6, c = threadIdx.x & 63;
    const float*  hb  = h + (size_t)b*NN*CC;
    const int*    isb = insrc + (size_t)b*EE;
    const float2* iwb = inw + (size_t)b*EE;
    #pragma unroll
    for (int g = 0; g < 2; g++){
        int n = n0 + w*2 + g;
        float hn = hb[(size_t)n*CC + c];
        int p0 = rowptr[b*(NN+1) + n];
        int p1 = rowptr[b*(NN+1) + n + 1];
        float a0 = 0.f, a1 = 0.f;
        int p = p0;
        for (; p + 4 <= p1; p += 4){
            int s0 = isb[p], s1 = isb[p+1], s2 = isb[p+2], s3 = isb[p+3];
            float2 w0 = iwb[p], w1 = iwb[p+1], w2 = iwb[p+2], w3 = iwb[p+3];
            float d0 = hb[(size_t)s0*CC + c] - hn;
            float d1 = hb[(size_t)s1*CC + c] - hn;
            float d2 = hb[(size_t)s2*CC + c] - hn;
            float d3 = hb[(size_t)s3*CC + c] - hn;
            a0 += w0.x*d0 + w1.x*d1 + w2.x*d2 + w3.x*d3;
            a1 += w0.y*d0 + w1.y*d1 + w2.y*d2 + w3.y*d3;
        }
        for (; p < p1; p++){
            int sx = isb[p]; float2 ww = iwb[p];
            float d = hb[(size_t)sx*CC + c] - hn;
            a0 += ww.x*d; a1 += ww.y*d;
        }
        ushort h0_, l0_, h1_, l1_;
        fsplit(a0, h0_, l0_);
        fsplit(a1, h1_, l1_);
        size_t sb2 = ((size_t)b*NN + n)*128 + 2*c;
        *(uint*)&segh[sb2] = pk2(h0_, h1_);
        *(uint*)&segl[sb2] = pk2(l0_, l1_);
    }
}

// D1: fwd (500) | grad (4000)
__global__ __launch_bounds__(256) void k_layer1(
    const ushort* __restrict__ hwH, const ushort* __restrict__ hwL,
    const ushort* __restrict__ wTH, const ushort* __restrict__ wTL,
    float* __restrict__ part,
    const float* __restrict__ hxcur, const int* __restrict__ rowptr,
    const int* __restrict__ insrc, const float2* __restrict__ inw,
    ushort* __restrict__ segh, ushort* __restrict__ segl){
    __shared__ __align__(16) char smem[32768];
    int bid = blockIdx.x;
    if (bid < BB*250){
        fwd_role(bid, smem, hwH, hwL, wTH, wTL, part);
    } else {
        grad_role(bid - BB*250, hxcur, rowptr, insrc, inw, segh, segl);
    }
}

// ---------------------------------------------------------------- partial reduce (round-3 proven)
__global__ __launch_bounds__(512) void k1_reduce(
    const float* __restrict__ part, float* __restrict__ Sc, float* __restrict__ Ss){
    int b = blockIdx.x >> 6, i = blockIdx.x & 63;   // grid B*64
    int t = threadIdx.x;
    int c = t & 255, sh = t >> 8;
    float a0=0,a1=0,a2=0,a3=0;
    int j = sh;
    for (; j + 6 < 250; j += 8){
        a0 += part[((size_t)(b*250 + j    )*64 + i)*256 + c];
        a1 += part[((size_t)(b*250 + j + 2)*64 + i)*256 + c];
        a2 += part[((size_t)(b*250 + j + 4)*64 + i)*256 + c];
        a3 += part[((size_t)(b*250 + j + 6)*64 + i)*256 + c];
    }
    for (; j < 250; j += 2)
        a0 += part[((size_t)(b*250 + j)*64 + i)*256 + c];
    float sum = (a0+a1)+(a2+a3);
    __shared__ float r2[256];
    if (sh) r2[c] = sum;
    __syncthreads();
    if (!sh){
        sum += r2[c];
        if (c < 128) Sc[(size_t)(b*64 + i)*128 + c] = sum;
        else         Ss[(size_t)(b*64 + i)*128 + (c - 128)] = sum;
    }
}

// ---------------------------------------------------------------- per-mode channel mix -> Wbig(hi/lo), bias
__global__ __launch_bounds__(256) void k2_mix(
    const float* __restrict__ Sc, const float* __restrict__ Ss,
    const float* __restrict__ part0,
    const float* __restrict__ wc, const float* __restrict__ wsp,
    const float* __restrict__ w0,
    const float* __restrict__ wsb, const float* __restrict__ gwsb,
    const float* __restrict__ wsW, const float* __restrict__ gwsW,
    ushort* __restrict__ WbH, ushort* __restrict__ WbL,
    float* __restrict__ bias, int l){
    int b = blockIdx.x >> 6, o = blockIdx.x & 63;
    int t = threadIdx.x;
    __shared__ float fc2s[2][128], fs2s[2][128];
    __shared__ float redp[4][64];
    __shared__ float red[64];
    {   // parallel part0 reduction (500 slices)
        int i = t & 63, grp = t >> 6;
        float a = 0.f;
        for (int s2 = grp; s2 < 500; s2 += 4)
            a += part0[(size_t)(b*500 + s2)*64 + i];
        redp[grp][i] = a;
    }
    int k = t & 127, hf = t >> 7;
    float fc = 0.f, fs = 0.f;
    for (int i = hf*32; i < hf*32 + 32; i++){
        float sc = Sc[(size_t)(b*CC + i)*KK + k];
        float ss = Ss[(size_t)(b*CC + i)*KK + k];
        size_t wi = (((size_t)l*CC + i)*CC + o)*KK + k;
        float a = wc[wi], bb2 = wsp[wi];
        fc += sc*a + ss*bb2;
        fs += sc*bb2 - ss*a;
    }
    fc2s[hf][k] = fc; fs2s[hf][k] = fs;
    __syncthreads();
    if (t < 64)
        red[t] = (redp[0][t]+redp[1][t]+redp[2][t]+redp[3][t]) * w0[((size_t)l*CC + t)*CC + o];
    size_t wb = (size_t)(b*CC + o) * 448;
    if (t < 128){
        float FC = fc2s[0][t] + fc2s[1][t];
        float FS = fs2s[0][t] + fs2s[1][t];
        ushort h_, l_;
        fsplit(2.f*FC, h_, l_);
        WbH[wb + t] = h_; WbL[wb + t] = l_;
        fsplit(-2.f*FS, h_, l_);
        WbH[wb + 128 + t] = h_; WbL[wb + 128 + t] = l_;
    }
    if (t >= 128 && t < 192){
        int q = t - 128;  // wsW 0..63
        float v = wsW[((size_t)l*CC + o)*CC + q];
        ushort h_, l_; fsplit(v, h_, l_);
        WbH[wb + 256 + q] = h_; WbL[wb + 256 + q] = l_;
    }
    if (t >= 128){
        int q = t - 128;  // gwsW 0..127
        float v = gwsW[((size_t)l*CC + o)*128 + q];
        ushort h_, l_; fsplit(v, h_, l_);
        WbH[wb + 320 + q] = h_; WbL[wb + 320 + q] = l_;
    }
    __syncthreads();
    if (t == 0){
        float f0 = 0.f;
        for (int i = 0; i < 64; i++) f0 += red[i];
        bias[b*CC + o] = f0 + wsb[l*CC + o] + gwsb[l*CC + o];
    }
}

// ---------------------------------------------------------------- layer output GEMM (MFMA split-bf16)
__global__ __launch_bounds__(256) void k3_gemm(
    const ushort* __restrict__ WbH, const ushort* __restrict__ WbL,
    const float* __restrict__ bias,
    const ushort* __restrict__ cbh, const ushort* __restrict__ cbl,
    const ushort* __restrict__ sbh, const ushort* __restrict__ sbl,
    const ushort* __restrict__ hxh, const ushort* __restrict__ hxl,
    const ushort* __restrict__ sgh, const ushort* __restrict__ sgl,
    const float* __restrict__ nw,
    float* __restrict__ hxO, ushort* __restrict__ hxhO, ushort* __restrict__ hxlO,
    ushort* __restrict__ hwhO, ushort* __restrict__ hwlO, float* __restrict__ part0,
    int doAux){
    int bid = blockIdx.x;              // B*125
    int b = bid / 125, s = bid % 125, x0 = s * 128;
    int t = threadIdx.x, l = t & 63, w = t >> 6;
    __shared__ __align__(16) char smem[34816];
    ushort* Vh = (ushort*)smem;
    ushort* Vl = Vh + 8192;
    __shared__ float nws[128];
    if (t < 128) nws[t] = nw[b*NN + x0 + t];
    f32x4 acc[8] = {};
    int o = w*16 + (l & 15);
    for (int cc = 0; cc < 7; cc++){
        const ushort *srcH, *srcL; int rl, co;
        switch (cc){
            case 0:  srcH = cbh; srcL = cbl; rl = 128; co = 0;  break;
            case 1:  srcH = cbh; srcL = cbl; rl = 128; co = 64; break;
            case 2:  srcH = sbh; srcL = sbl; rl = 128; co = 0;  break;
            case 3:  srcH = sbh; srcL = sbl; rl = 128; co = 64; break;
            case 4:  srcH = hxh; srcL = hxl; rl = 64;  co = 0;  break;
            case 5:  srcH = sgh; srcL = sgl; rl = 128; co = 0;  break;
            default: srcH = sgh; srcL = sgl; rl = 128; co = 64; break;
        }
        __syncthreads();
        #pragma unroll
        for (int it = 0; it < 4; it++){
            int u = it*256 + t;
            int xl2 = u >> 3, q = u & 7;
            size_t g = (size_t)(b*NN + x0 + xl2)*rl + co + q*8;
            uint4 vh = *(const uint4*)&srcH[g];
            uint4 vl2 = *(const uint4*)&srcL[g];
            int ldsb = xl2*128 + ((q*16) ^ ((xl2 & 7) << 4));
            *(uint4*)&Vh[ldsb >> 1] = vh;
            *(uint4*)&Vl[ldsb >> 1] = vl2;
        }
        __syncthreads();
        bf16x8 Ah[2], Al[2];
        #pragma unroll
        for (int ks = 0; ks < 2; ks++){
            size_t ab = (size_t)(b*64 + o)*448 + cc*64 + ks*32 + ((l >> 4) * 8);
            Ah[ks] = *reinterpret_cast<const bf16x8*>(&WbH[ab]);
            Al[ks] = *reinterpret_cast<const bf16x8*>(&WbL[ab]);
        }
        #pragma unroll
        for (int nt = 0; nt < 8; nt++){
            int xc = nt*16 + (l & 15);
            #pragma unroll
            for (int ks = 0; ks < 2; ks++){
                int boff = xc*128 + (((ks*64) + ((l >> 4) * 16)) ^ ((xc & 7) << 4));
                bf16x8 bh = *reinterpret_cast<const bf16x8*>(&Vh[boff >> 1]);
                bf16x8 bl = *reinterpret_cast<const bf16x8*>(&Vl[boff >> 1]);
                acc[nt] = __builtin_amdgcn_mfma_f32_16x16x32_bf16(Ah[ks], bh, acc[nt], 0, 0, 0);
                acc[nt] = __builtin_amdgcn_mfma_f32_16x16x32_bf16(Ah[ks], bl, acc[nt], 0, 0, 0);
                acc[nt] = __builtin_amdgcn_mfma_f32_16x16x32_bf16(Al[ks], bh, acc[nt], 0, 0, 0);
            }
        }
    }
    __syncthreads();
    float* ot = (float*)smem;          // reuse as [128][68]
    float bv[4];
    #pragma unroll
    for (int r = 0; r < 4; r++) bv[r] = bias[b*64 + w*16 + (l >> 4)*4 + r];
    #pragma unroll
    for (int nt = 0; nt < 8; nt++){
        int xc = nt*16 + (l & 15);
        #pragma unroll
        for (int r = 0; r < 4; r++){
            float v = acc[nt][r] + bv[r];
            if (doAux) v = gelu_f(v);
            ot[xc*68 + (w*16 + (l >> 4)*4 + r)] = v;
        }
    }
    __syncthreads();
    write_h_outputs(ot, nws, b, s, x0, t, doAux, hxO, hxhO, hxlO, hwhO, hwlO, part0);
}

// ---------------------------------------------------------------- head: gelu(fc1) -> fc2
__global__ __launch_bounds__(256) void k_head(
    const float* __restrict__ h, const float* __restrict__ W1,
    const float* __restrict__ b1, const float* __restrict__ W2,
    const float* __restrict__ b2, float* __restrict__ out){
    int bid = blockIdx.x;              // B * 250
    int b = bid / 250, n0 = (bid % 250) * 64;
    int t = threadIdx.x, w = t >> 6, f = t & 63;
    __shared__ float Wl[128][65];
    #pragma unroll
    for (int r = 0; r < 8; r++){
        int u = r*256 + t;
        int ff = u >> 4, cq = u & 15;
        float4 v = *(const float4*)&W1[ff*64 + cq*4];
        Wl[ff][cq*4+0] = v.x; Wl[ff][cq*4+1] = v.y;
        Wl[ff][cq*4+2] = v.z; Wl[ff][cq*4+3] = v.w;
    }
    __syncthreads();
    float w2a = W2[f], w2b = W2[64+f];
    float b1a = b1[f], b1b = b1[64+f];
    float b2v = b2[0];
    for (int g = 0; g < 16; g++){
        int n = n0 + w*16 + g;
        float hv = h[((size_t)b*NN + n)*CC + f];
        float a1 = b1a, a2 = b1b;
        #pragma unroll
        for (int c2 = 0; c2 < 64; c2++){
            float xv = __shfl(hv, c2, 64);
            a1 += Wl[f][c2] * xv;
            a2 += Wl[64+f][c2] * xv;
        }
        float p = gelu_f(a1)*w2a + gelu_f(a2)*w2b;
        for (int off = 32; off; off >>= 1) p += __shfl_down(p, off, 64);
        if (f == 0) out[(size_t)b*NN + n] = p + b2v;
    }
}

// ---------------------------------------------------------------- host
extern "C" void kernel_launch(void* const* d_in, const int* in_sizes, int n_in,
                              void* d_out, int out_size, void* d_ws, size_t ws_size,
                              hipStream_t stream){
    const float* x_in  = (const float*)d_in[0];
    const float* nodes = (const float*)d_in[2];
    const float* nw    = (const float*)d_in[3];
    const int*   edges = (const int*)d_in[4];
    const float* egw   = (const float*)d_in[5];
    const float* modes = (const float*)d_in[6];
    const float* latent= (const float*)d_in[7];
    const float* fc0W  = (const float*)d_in[8];
    const float* fc0b  = (const float*)d_in[9];
    const float* wc    = (const float*)d_in[10];
    const float* wsp   = (const float*)d_in[11];
    const float* w0    = (const float*)d_in[12];
    const float* wsW   = (const float*)d_in[13];
    const float* wsb   = (const float*)d_in[14];
    const float* gwsW  = (const float*)d_in[15];
    const float* gwsb  = (const float*)d_in[16];
    const float* fc1W  = (const float*)d_in[17];
    const float* fc1b  = (const float*)d_in[18];
    const float* fc2W  = (const float*)d_in[19];
    const float* fc2b  = (const float*)d_in[20];
    float* out = (float*)d_out;

    char* wsbase = (char*)d_ws;
    size_t off = 0;
    auto alloc = [&](size_t bytes) -> void* {
        void* p = wsbase + off;
        off += (bytes + 255) & ~(size_t)255;
        return p;
    };
    ushort* cbh = (ushort*)alloc((size_t)BB*NN*128*2);
    ushort* cbl = (ushort*)alloc((size_t)BB*NN*128*2);
    ushort* sbh = (ushort*)alloc((size_t)BB*NN*128*2);
    ushort* sbl = (ushort*)alloc((size_t)BB*NN*128*2);
    ushort* wTh = (ushort*)alloc((size_t)BB*256*NN*2);
    ushort* wTl = (ushort*)alloc((size_t)BB*256*NN*2);
    float*  hx[2];  ushort* hxh[2]; ushort* hxl[2]; ushort* hwh[2]; ushort* hwl[2];
    for (int i = 0; i < 2; i++){
        hx[i]  = (float*) alloc((size_t)BB*NN*64*4);
        hxh[i] = (ushort*)alloc((size_t)BB*NN*64*2);
        hxl[i] = (ushort*)alloc((size_t)BB*NN*64*2);
        hwh[i] = (ushort*)alloc((size_t)BB*64*NN*2);
        hwl[i] = (ushort*)alloc((size_t)BB*64*NN*2);
    }
    ushort* segh = (ushort*)alloc((size_t)BB*NN*128*2);
    ushort* segl = (ushort*)alloc((size_t)BB*NN*128*2);
    float*  part = (float*) alloc((size_t)BB*250*64*256*4);
    float*  part0= (float*) alloc((size_t)BB*125*4*64*4);
    float*  Sc   = (float*) alloc((size_t)BB*64*128*4);
    float*  Ss   = (float*) alloc((size_t)BB*64*128*4);
    ushort* WbH  = (ushort*)alloc((size_t)BB*64*448*2);
    ushort* WbL  = (ushort*)alloc((size_t)BB*64*448*2);
    float*  bias = (float*) alloc((size_t)BB*64*4);
    int*   cnt   = (int*)   alloc((size_t)BB*NN*4);
    int*   rowptr= (int*)   alloc((size_t)BB*(NN+4)*4);
    int*   cursor= (int*)   alloc((size_t)BB*NN*4);
    int*   insrc = (int*)   alloc((size_t)BB*EE*4);
    float2* inw  = (float2*)alloc((size_t)BB*EE*8);

    // S1: bases | fc0 | zero-cnt  (875 blocks)
    k_start<<<BB*250 + BB*125 + 125, 256, 0, stream>>>(
        nodes, modes, latent, nw, x_in, fc0W, fc0b,
        cbh, cbl, sbh, sbl, wTh, wTl,
        hx[0], hxh[0], hxl[0], hwh[0], hwl[0], part0, cnt);

    csr_hist<<<(BB*EE+255)/256, 256, 0, stream>>>(edges, cnt);
    csr_scan<<<BB, 1024, 0, stream>>>(cnt, rowptr, cursor);
    csr_fill<<<(BB*EE+255)/256, 256, 0, stream>>>(edges, egw, cursor, insrc, inw);

    int cur = 0;
    for (int l = 0; l < LL; l++){
        int nxt = cur ^ 1;
        int doAux = (l < LL-1) ? 1 : 0;
        k_layer1<<<BB*250 + BB*2000, 256, 0, stream>>>(
            hwh[cur], hwl[cur], wTh, wTl, part,
            hx[cur], rowptr, insrc, inw, segh, segl);
        k1_reduce<<<BB*64, 512, 0, stream>>>(part, Sc, Ss);
        k2_mix<<<BB*64, 256, 0, stream>>>(Sc, Ss, part0, wc, wsp, w0, wsb, gwsb,
                                          wsW, gwsW, WbH, WbL, bias, l);
        k3_gemm<<<BB*125, 256, 0, stream>>>(WbH, WbL, bias,
                                            cbh, cbl, sbh, sbl,
                                            hxh[cur], hxl[cur], segh, segl, nw,
                                            hx[nxt], hxh[nxt], hxl[nxt],
                                            hwh[nxt], hwl[nxt], part0, doAux);
        cur = nxt;
    }
    k_head<<<BB*250, 256, 0, stream>>>(hx[cur], fc1W, fc1b, fc2W, fc2b, out);
    (void)in_sizes; (void)n_in; (void)out_size; (void)ws_size;
}

// Round 6
// 552.924 us; speedup vs baseline: 1.0466x; 1.0466x over previous
//
#include <hip/hip_runtime.h>
#include <math.h>

#define BB 2
#define NN 16000
#define EE 160000
#define KK 128
#define CC 64
#define LL 3

typedef __attribute__((ext_vector_type(8))) short bf16x8;
typedef __attribute__((ext_vector_type(4))) float f32x4;

__device__ __forceinline__ float gelu_f(float x){
    float x3 = x * x * x;
    return 0.5f * x * (1.f + tanhf(0.7978845608028654f * (x + 0.044715f * x3)));
}
__device__ __forceinline__ ushort f2bf(float f){
    uint u = __float_as_uint(f);
    u += 0x7fff + ((u >> 16) & 1);
    return (ushort)(u >> 16);
}
__device__ __forceinline__ float bf2f(ushort h){ return __uint_as_float(((uint)h) << 16); }
__device__ __forceinline__ void fsplit(float v, ushort &hi, ushort &lo){
    hi = f2bf(v);
    lo = f2bf(v - bf2f(hi));
}
__device__ __forceinline__ uint pk2(ushort a, ushort b){ return (uint)a | ((uint)b << 16); }

// ---------------------------------------------------------------- bases
// cb/sb x-major HI [b][x][128]; wT UNWEIGHTED k-major HI [b][256][16000]
__global__ __launch_bounds__(256) void k_bases(
    const float* __restrict__ nodes, const float* __restrict__ modes,
    const float* __restrict__ latent,
    ushort* __restrict__ cbh, ushort* __restrict__ sbh,
    ushort* __restrict__ wTh){
    int bid = blockIdx.x;              // B*250
    int b = bid / 250, x0 = (bid % 250) * 64;
    int t = threadIdx.x;
    __shared__ float sm0[128], sm1[128];
    __shared__ uint tc[64][65], ts[64][65];
    if (t < 128){
        float i0 = 0.5f + 1.5f / (1.f + expf(-latent[0]));
        float i1 = 0.5f + 1.5f / (1.f + expf(-latent[1]));
        sm0[t] = modes[t*2+0] * i0;
        sm1[t] = modes[t*2+1] * i1;
    }
    __syncthreads();
    int xloc = t & 63;
    float n0 = nodes[((size_t)b*NN + x0 + xloc)*2 + 0];
    float n1 = nodes[((size_t)b*NN + x0 + xloc)*2 + 1];
    for (int kh = 0; kh < 2; kh++){
        int kq = t >> 6;
        #pragma unroll
        for (int j = 0; j < 16; j++){
            int kl = kq*16 + j;
            int k = kh*64 + kl;
            float tmp = n0*sm0[k] + n1*sm1[k];
            float sv, cv; sincosf(tmp, &sv, &cv);
            tc[xloc][kl] = (uint)f2bf(cv);
            ts[xloc][kl] = (uint)f2bf(sv);
        }
        __syncthreads();
        {   // cb/sb x-major hi
            int q = t >> 6;
            size_t base = ((size_t)b*NN + x0 + xloc)*128 + kh*64 + q*16;
            #pragma unroll
            for (int g2 = 0; g2 < 2; g2++){
                uint u0 = tc[xloc][q*16 + g2*8 + 0], u1 = tc[xloc][q*16 + g2*8 + 1];
                uint u2 = tc[xloc][q*16 + g2*8 + 2], u3 = tc[xloc][q*16 + g2*8 + 3];
                uint u4 = tc[xloc][q*16 + g2*8 + 4], u5 = tc[xloc][q*16 + g2*8 + 5];
                uint u6 = tc[xloc][q*16 + g2*8 + 6], u7 = tc[xloc][q*16 + g2*8 + 7];
                uint4 vh;
                vh.x = pk2((ushort)u0,(ushort)u1); vh.y = pk2((ushort)u2,(ushort)u3);
                vh.z = pk2((ushort)u4,(ushort)u5); vh.w = pk2((ushort)u6,(ushort)u7);
                *(uint4*)&cbh[base + g2*8] = vh;
                u0 = ts[xloc][q*16 + g2*8 + 0]; u1 = ts[xloc][q*16 + g2*8 + 1];
                u2 = ts[xloc][q*16 + g2*8 + 2]; u3 = ts[xloc][q*16 + g2*8 + 3];
                u4 = ts[xloc][q*16 + g2*8 + 4]; u5 = ts[xloc][q*16 + g2*8 + 5];
                u6 = ts[xloc][q*16 + g2*8 + 6]; u7 = ts[xloc][q*16 + g2*8 + 7];
                vh.x = pk2((ushort)u0,(ushort)u1); vh.y = pk2((ushort)u2,(ushort)u3);
                vh.z = pk2((ushort)u4,(ushort)u5); vh.w = pk2((ushort)u6,(ushort)u7);
                *(uint4*)&sbh[base + g2*8] = vh;
            }
        }
        {   // wT k-major UNWEIGHTED hi
            int k = t & 63, g = t >> 6;
            int kgc = kh*64 + k;
            int kgs = 128 + kh*64 + k;
            ushort hc[16], hs[16];
            #pragma unroll
            for (int j = 0; j < 16; j++){
                int xx = g*16 + j;
                hc[j] = (ushort)tc[xx][k];
                hs[j] = (ushort)ts[xx][k];
            }
            size_t wbc = ((size_t)b*256 + kgc)*16000 + x0 + g*16;
            size_t wbs = ((size_t)b*256 + kgs)*16000 + x0 + g*16;
            uint4 v;
            v.x = pk2(hc[0],hc[1]); v.y = pk2(hc[2],hc[3]); v.z = pk2(hc[4],hc[5]); v.w = pk2(hc[6],hc[7]);
            *(uint4*)&wTh[wbc] = v;
            v.x = pk2(hc[8],hc[9]); v.y = pk2(hc[10],hc[11]); v.z = pk2(hc[12],hc[13]); v.w = pk2(hc[14],hc[15]);
            *(uint4*)&wTh[wbc + 8] = v;
            v.x = pk2(hs[0],hs[1]); v.y = pk2(hs[2],hs[3]); v.z = pk2(hs[4],hs[5]); v.w = pk2(hs[6],hs[7]);
            *(uint4*)&wTh[wbs] = v;
            v.x = pk2(hs[8],hs[9]); v.y = pk2(hs[10],hs[11]); v.z = pk2(hs[12],hs[13]); v.w = pk2(hs[14],hs[15]);
            *(uint4*)&wTh[wbs + 8] = v;
        }
        __syncthreads();
    }
}

// ---------------------------------------------------------------- shared epilogue
__device__ __forceinline__ void write_h_outputs(
    const float* ot, const float* nws, int b, int s, int x0, int t, int doAux,
    float* __restrict__ hx, ushort* __restrict__ hxh, ushort* __restrict__ hxl,
    ushort* __restrict__ hwh, float* __restrict__ part0){
    {
        int xl = t >> 1, half = t & 1;
        size_t gb = ((size_t)b*NN + x0 + xl)*64 + half*32;
        const float* row = &ot[xl*68 + half*32];
        #pragma unroll
        for (int j = 0; j < 8; j++){
            float4 v; v.x = row[j*4]; v.y = row[j*4+1]; v.z = row[j*4+2]; v.w = row[j*4+3];
            *(float4*)&hx[gb + j*4] = v;
        }
        if (doAux){
            #pragma unroll
            for (int q = 0; q < 4; q++){
                ushort h_[8], l_[8];
                #pragma unroll
                for (int j = 0; j < 8; j++) fsplit(row[q*8 + j], h_[j], l_[j]);
                uint4 vh, vl;
                vh.x = pk2(h_[0],h_[1]); vh.y = pk2(h_[2],h_[3]); vh.z = pk2(h_[4],h_[5]); vh.w = pk2(h_[6],h_[7]);
                vl.x = pk2(l_[0],l_[1]); vl.y = pk2(l_[2],l_[3]); vl.z = pk2(l_[4],l_[5]); vl.w = pk2(l_[6],l_[7]);
                *(uint4*)&hxh[gb + q*8] = vh;
                *(uint4*)&hxl[gb + q*8] = vl;
            }
        }
    }
    if (doAux){
        int i = t & 63, g = t >> 6;
        float a = 0.f;
        #pragma unroll
        for (int rep = 0; rep < 4; rep++){
            int xs = g*32 + rep*8;
            ushort h_[8];
            #pragma unroll
            for (int j = 0; j < 8; j++){
                float v = ot[(xs + j)*68 + i] * nws[xs + j];
                a += v;
                h_[j] = f2bf(v);
            }
            uint4 vh;
            vh.x = pk2(h_[0],h_[1]); vh.y = pk2(h_[2],h_[3]); vh.z = pk2(h_[4],h_[5]); vh.w = pk2(h_[6],h_[7]);
            size_t wb = (size_t)(b*64 + i)*16000 + x0 + xs;
            *(uint4*)&hwh[wb] = vh;
        }
        part0[((size_t)(b*125 + s)*4 + g)*64 + i] = a;
    }
}

// ---------------------------------------------------------------- fc0
__global__ __launch_bounds__(256) void k_fc0(
    const float* __restrict__ x, const float* __restrict__ W,
    const float* __restrict__ bb, const float* __restrict__ nw,
    float* __restrict__ hx, ushort* __restrict__ hxh, ushort* __restrict__ hxl,
    ushort* __restrict__ hwh, float* __restrict__ part0){
    int bid = blockIdx.x;              // B*125
    int b = bid / 125, s = bid % 125;
    int x0 = s * 128;
    int t = threadIdx.x;
    __shared__ float ot[128*68];
    __shared__ float nws[128];
    __shared__ float Wf[192], bf_[64];
    if (t < 192) Wf[t] = W[t];
    if (t < 64) bf_[t] = bb[t];
    if (t < 128) nws[t] = nw[b*NN + x0 + t];
    __syncthreads();
    {
        int xl = t >> 1, half = t & 1;
        float v0 = x[((size_t)b*NN + x0 + xl)*3 + 0];
        float v1 = x[((size_t)b*NN + x0 + xl)*3 + 1];
        float v2 = x[((size_t)b*NN + x0 + xl)*3 + 2];
        #pragma unroll
        for (int j = 0; j < 32; j++){
            int o = half*32 + j;
            ot[xl*68 + o] = Wf[o*3]*v0 + Wf[o*3+1]*v1 + Wf[o*3+2]*v2 + bf_[o];
        }
    }
    __syncthreads();
    write_h_outputs(ot, nws, b, s, x0, t, 1, hx, hxh, hxl, hwh, part0);
}

// ---------------------------------------------------------------- CSR build
__global__ __launch_bounds__(256) void csr_hist(
    const int* __restrict__ edges, int* __restrict__ cnt){
    int idx = blockIdx.x * 256 + threadIdx.x;
    if (idx >= BB*EE) return;
    int b = idx / EE;
    int tgt = edges[(size_t)idx*2];
    atomicAdd(&cnt[b*NN + tgt], 1);
}

__global__ __launch_bounds__(1024) void csr_scan(
    const int* __restrict__ cnt, int* __restrict__ rowptr, int* __restrict__ cursor){
    int b = blockIdx.x;
    int t = threadIdx.x;
    __shared__ int lds[1024];
    int base = t * 16;
    int v[16];
    int run = 0;
    #pragma unroll
    for (int j = 0; j < 16; j++){
        int n = base + j;
        int c = (n < NN) ? cnt[b*NN + n] : 0;
        v[j] = run;
        run += c;
    }
    lds[t] = run;
    __syncthreads();
    for (int off = 1; off < 1024; off <<= 1){
        int xv = (t >= off) ? lds[t-off] : 0;
        __syncthreads();
        lds[t] += xv;
        __syncthreads();
    }
    int toff = lds[t] - run;  // exclusive
    #pragma unroll
    for (int j = 0; j < 16; j++){
        int n = base + j;
        if (n < NN){
            int p = toff + v[j];
            rowptr[b*(NN+1) + n] = p;
            cursor[b*NN + n] = p;
        }
    }
    if (t == 1023) rowptr[b*(NN+1) + NN] = lds[1023];
}

__global__ __launch_bounds__(256) void csr_fill(
    const int* __restrict__ edges, const float* __restrict__ egw,
    int* __restrict__ cursor, int* __restrict__ insrc, float2* __restrict__ inw){
    int idx = blockIdx.x * 256 + threadIdx.x;
    if (idx >= BB*EE) return;
    int b = idx / EE;
    int tgt = edges[(size_t)idx*2];
    int src = edges[(size_t)idx*2 + 1];
    int pos = atomicAdd(&cursor[b*NN + tgt], 1);
    insrc[(size_t)b*EE + pos] = src;
    const float2 wv = *(const float2*)&egw[(size_t)idx*2];
    inw[(size_t)b*EE + pos] = wv;
}

// ---------------------------------------------------------------- forward transform: pure-bf16 MFMA (hi only)
__global__ __launch_bounds__(256) void k1_fwd(
    const ushort* __restrict__ hwH,
    const ushort* __restrict__ wTH,
    float* __restrict__ part){
    int bid = blockIdx.x;              // B*250
    int b = bid / 250, s = bid % 250;
    int x0 = s * 64;
    int t = threadIdx.x, l = t & 63, w = t >> 6;
    __shared__ __align__(16) ushort Bh[128*64];
    f32x4 acc[16] = {};
    bf16x8 Ah[2];
    int i = w*16 + (l & 15);
    #pragma unroll
    for (int ks = 0; ks < 2; ks++){
        size_t ab = (size_t)(b*64 + i)*16000 + x0 + ks*32 + ((l >> 4) * 8);
        Ah[ks] = *reinterpret_cast<const bf16x8*>(&hwH[ab]);
    }
    for (int p = 0; p < 2; p++){
        if (p) __syncthreads();
        #pragma unroll
        for (int it = 0; it < 4; it++){
            int u = it*256 + t;
            int kloc = u >> 3, q = u & 7;
            size_t g = ((size_t)(b*256 + p*128 + kloc))*16000 + x0 + q*8;
            uint4 vh = *(const uint4*)&wTH[g];
            int ldsb = kloc*128 + ((q*16) ^ ((kloc & 7) << 4));
            *(uint4*)&Bh[ldsb >> 1] = vh;
        }
        __syncthreads();
        #pragma unroll
        for (int kt = 0; kt < 8; kt++){
            int kcol = kt*16 + (l & 15);
            int ai = p*8 + kt;
            #pragma unroll
            for (int ks = 0; ks < 2; ks++){
                int boff = kcol*128 + (((ks*64) + ((l >> 4) * 16)) ^ ((kcol & 7) << 4));
                bf16x8 bh = *reinterpret_cast<const bf16x8*>(&Bh[boff >> 1]);
                acc[ai] = __builtin_amdgcn_mfma_f32_16x16x32_bf16(Ah[ks], bh, acc[ai], 0, 0, 0);
            }
        }
    }
    size_t pb = (size_t)(b*250 + s) * 64 * 256;
    #pragma unroll
    for (int nt = 0; nt < 16; nt++){
        #pragma unroll
        for (int r = 0; r < 4; r++){
            int irow = w*16 + (l >> 4)*4 + r;
            part[pb + (size_t)irow*256 + nt*16 + (l & 15)] = acc[nt][r];
        }
    }
}

// ---------------------------------------------------------------- partial reduce (256 blocks, coalesced)
__global__ __launch_bounds__(256) void k1_reduce(
    const float* __restrict__ part, float* __restrict__ Sc, float* __restrict__ Ss){
    int bid = blockIdx.x;          // BB*128: (b, i, half)
    int b = bid >> 7, rr = bid & 127;
    int i = rr >> 1, half = rr & 1;
    int t = threadIdx.x;
    int c = half*128 + (t & 127), sh = t >> 7;
    const float* pb = part + ((size_t)b*16000 + i)*256 + c;
    float a0=0,a1=0,a2=0,a3=0;
    int j = sh;
    for (; j + 6 < 250; j += 8){
        a0 += pb[(size_t)(j    )*16384];
        a1 += pb[(size_t)(j + 2)*16384];
        a2 += pb[(size_t)(j + 4)*16384];
        a3 += pb[(size_t)(j + 6)*16384];
    }
    for (; j < 250; j += 2) a0 += pb[(size_t)j*16384];
    float sum = (a0+a1)+(a2+a3);
    __shared__ float r2[128];
    if (sh) r2[t & 127] = sum;
    __syncthreads();
    if (!sh){
        sum += r2[t & 127];
        if (c < 128) Sc[(size_t)(b*64 + i)*128 + c] = sum;
        else         Ss[(size_t)(b*64 + i)*128 + (c - 128)] = sum;
    }
}

// ---------------------------------------------------------------- per-mode channel mix -> Wbig(hi/lo), bias
__global__ __launch_bounds__(256) void k2_mix(
    const float* __restrict__ Sc, const float* __restrict__ Ss,
    const float* __restrict__ part0,
    const float* __restrict__ wc, const float* __restrict__ wsp,
    const float* __restrict__ w0,
    const float* __restrict__ wsb, const float* __restrict__ gwsb,
    const float* __restrict__ wsW, const float* __restrict__ gwsW,
    ushort* __restrict__ WbH, ushort* __restrict__ WbL,
    float* __restrict__ bias, int l){
    int b = blockIdx.x >> 6, o = blockIdx.x & 63;
    int t = threadIdx.x;
    __shared__ float fc2s[2][128], fs2s[2][128];
    __shared__ float redp[4][64];
    __shared__ float red[64];
    {   // parallel part0 reduction (500 slices)
        int i = t & 63, grp = t >> 6;
        float a = 0.f;
        for (int s2 = grp; s2 < 500; s2 += 4)
            a += part0[(size_t)(b*500 + s2)*64 + i];
        redp[grp][i] = a;
    }
    int k = t & 127, hf = t >> 7;
    float fc = 0.f, fs = 0.f;
    for (int i = hf*32; i < hf*32 + 32; i++){
        float sc = Sc[(size_t)(b*CC + i)*KK + k];
        float ss = Ss[(size_t)(b*CC + i)*KK + k];
        size_t wi = (((size_t)l*CC + i)*CC + o)*KK + k;
        float a = wc[wi], bb2 = wsp[wi];
        fc += sc*a + ss*bb2;
        fs += sc*bb2 - ss*a;
    }
    fc2s[hf][k] = fc; fs2s[hf][k] = fs;
    __syncthreads();
    if (t < 64)
        red[t] = (redp[0][t]+redp[1][t]+redp[2][t]+redp[3][t]) * w0[((size_t)l*CC + t)*CC + o];
    size_t wb = (size_t)(b*CC + o) * 448;
    if (t < 128){
        float FC = fc2s[0][t] + fc2s[1][t];
        float FS = fs2s[0][t] + fs2s[1][t];
        ushort h_, l_;
        fsplit(2.f*FC, h_, l_);
        WbH[wb + t] = h_; WbL[wb + t] = l_;
        fsplit(-2.f*FS, h_, l_);
        WbH[wb + 128 + t] = h_; WbL[wb + 128 + t] = l_;
    }
    if (t >= 128 && t < 192){
        int q = t - 128;  // wsW 0..63
        float v = wsW[((size_t)l*CC + o)*CC + q];
        ushort h_, l_; fsplit(v, h_, l_);
        WbH[wb + 256 + q] = h_; WbL[wb + 256 + q] = l_;
    }
    if (t >= 128){
        int q = t - 128;  // gwsW 0..127
        float v = gwsW[((size_t)l*CC + o)*128 + q];
        ushort h_, l_; fsplit(v, h_, l_);
        WbH[wb + 320 + q] = h_; WbL[wb + 320 + q] = l_;
    }
    __syncthreads();
    if (t == 0){
        float f0 = 0.f;
        for (int i = 0; i < 64; i++) f0 += red[i];
        bias[b*CC + o] = f0 + wsb[l*CC + o] + gwsb[l*CC + o];
    }
}

// ---------------------------------------------------------------- gradient field (CSR, atomic-free, no LDS)
__global__ __launch_bounds__(256) void k_grad(
    const float* __restrict__ h, const int* __restrict__ rowptr,
    const int* __restrict__ insrc, const float2* __restrict__ inw,
    ushort* __restrict__ segh, ushort* __restrict__ segl){
    int bid = blockIdx.x;              // B * 2000
    int b = bid / 2000, n0 = (bid % 2000) * 8;
    int w = threadIdx.x >> 6, c = threadIdx.x & 63;
    const float*  hb  = h + (size_t)b*NN*CC;
    const int*    isb = insrc + (size_t)b*EE;
    const float2* iwb = inw + (size_t)b*EE;
    #pragma unroll
    for (int g = 0; g < 2; g++){
        int n = n0 + w*2 + g;
        float hn = hb[(size_t)n*CC + c];
        int p0 = rowptr[b*(NN+1) + n];
        int p1 = rowptr[b*(NN+1) + n + 1];
        float a0 = 0.f, a1 = 0.f;
        int p = p0;
        for (; p + 4 <= p1; p += 4){
            int s0 = isb[p], s1 = isb[p+1], s2 = isb[p+2], s3 = isb[p+3];
            float2 w0 = iwb[p], w1 = iwb[p+1], w2 = iwb[p+2], w3 = iwb[p+3];
            float d0 = hb[(size_t)s0*CC + c] - hn;
            float d1 = hb[(size_t)s1*CC + c] - hn;
            float d2 = hb[(size_t)s2*CC + c] - hn;
            float d3 = hb[(size_t)s3*CC + c] - hn;
            a0 += w0.x*d0 + w1.x*d1 + w2.x*d2 + w3.x*d3;
            a1 += w0.y*d0 + w1.y*d1 + w2.y*d2 + w3.y*d3;
        }
        for (; p < p1; p++){
            int sx = isb[p]; float2 ww = iwb[p];
            float d = hb[(size_t)sx*CC + c] - hn;
            a0 += ww.x*d; a1 += ww.y*d;
        }
        ushort h0_, l0_, h1_, l1_;
        fsplit(a0, h0_, l0_);
        fsplit(a1, h1_, l1_);
        size_t sb2 = ((size_t)b*NN + n)*128 + 2*c;
        *(uint*)&segh[sb2] = pk2(h0_, h1_);
        *(uint*)&segl[sb2] = pk2(l0_, l1_);
    }
}

// ---------------------------------------------------------------- layer output GEMM (tiered precision)
__global__ __launch_bounds__(256) void k3_gemm(
    const ushort* __restrict__ WbH, const ushort* __restrict__ WbL,
    const float* __restrict__ bias,
    const ushort* __restrict__ cbh, const ushort* __restrict__ sbh,
    const ushort* __restrict__ hxh, const ushort* __restrict__ hxl,
    const ushort* __restrict__ sgh, const ushort* __restrict__ sgl,
    const float* __restrict__ nw,
    float* __restrict__ hxO, ushort* __restrict__ hxhO, ushort* __restrict__ hxlO,
    ushort* __restrict__ hwhO, float* __restrict__ part0,
    int doAux){
    int bid = blockIdx.x;              // B*125
    int b = bid / 125, s = bid % 125, x0 = s * 128;
    int t = threadIdx.x, l = t & 63, w = t >> 6;
    __shared__ __align__(16) char smem[34816];
    ushort* Vh = (ushort*)smem;
    ushort* Vl = Vh + 8192;
    __shared__ float nws[128];
    if (t < 128) nws[t] = nw[b*NN + x0 + t];
    f32x4 acc[8] = {};
    int o = w*16 + (l & 15);
    for (int cc = 0; cc < 7; cc++){
        const ushort *srcH, *srcL; int rl, co, lo;
        switch (cc){
            case 0:  srcH = cbh; srcL = cbh; rl = 128; co = 0;  lo = 0; break;
            case 1:  srcH = cbh; srcL = cbh; rl = 128; co = 64; lo = 0; break;
            case 2:  srcH = sbh; srcL = sbh; rl = 128; co = 0;  lo = 0; break;
            case 3:  srcH = sbh; srcL = sbh; rl = 128; co = 64; lo = 0; break;
            case 4:  srcH = hxh; srcL = hxl; rl = 64;  co = 0;  lo = 1; break;
            case 5:  srcH = sgh; srcL = sgl; rl = 128; co = 0;  lo = 1; break;
            default: srcH = sgh; srcL = sgl; rl = 128; co = 64; lo = 1; break;
        }
        __syncthreads();
        #pragma unroll
        for (int it = 0; it < 4; it++){
            int u = it*256 + t;
            int xl2 = u >> 3, q = u & 7;
            size_t g = (size_t)(b*NN + x0 + xl2)*rl + co + q*8;
            uint4 vh = *(const uint4*)&srcH[g];
            int ldsb = xl2*128 + ((q*16) ^ ((xl2 & 7) << 4));
            *(uint4*)&Vh[ldsb >> 1] = vh;
            if (lo){
                uint4 vl2 = *(const uint4*)&srcL[g];
                *(uint4*)&Vl[ldsb >> 1] = vl2;
            }
        }
        __syncthreads();
        bf16x8 Ah[2], Al[2];
        #pragma unroll
        for (int ks = 0; ks < 2; ks++){
            size_t ab = (size_t)(b*64 + o)*448 + cc*64 + ks*32 + ((l >> 4) * 8);
            Ah[ks] = *reinterpret_cast<const bf16x8*>(&WbH[ab]);
            Al[ks] = *reinterpret_cast<const bf16x8*>(&WbL[ab]);
        }
        #pragma unroll
        for (int nt = 0; nt < 8; nt++){
            int xc = nt*16 + (l & 15);
            #pragma unroll
            for (int ks = 0; ks < 2; ks++){
                int boff = xc*128 + (((ks*64) + ((l >> 4) * 16)) ^ ((xc & 7) << 4));
                bf16x8 bh = *reinterpret_cast<const bf16x8*>(&Vh[boff >> 1]);
                acc[nt] = __builtin_amdgcn_mfma_f32_16x16x32_bf16(Ah[ks], bh, acc[nt], 0, 0, 0);
                if (lo){
                    bf16x8 bl = *reinterpret_cast<const bf16x8*>(&Vl[boff >> 1]);
                    acc[nt] = __builtin_amdgcn_mfma_f32_16x16x32_bf16(Ah[ks], bl, acc[nt], 0, 0, 0);
                    acc[nt] = __builtin_amdgcn_mfma_f32_16x16x32_bf16(Al[ks], bh, acc[nt], 0, 0, 0);
                }
            }
        }
    }
    __syncthreads();
    float* ot = (float*)smem;          // reuse as [128][68]
    float bv[4];
    #pragma unroll
    for (int r = 0; r < 4; r++) bv[r] = bias[b*64 + w*16 + (l >> 4)*4 + r];
    #pragma unroll
    for (int nt = 0; nt < 8; nt++){
        int xc = nt*16 + (l & 15);
        #pragma unroll
        for (int r = 0; r < 4; r++){
            float v = acc[nt][r] + bv[r];
            if (doAux) v = gelu_f(v);
            ot[xc*68 + (w*16 + (l >> 4)*4 + r)] = v;
        }
    }
    __syncthreads();
    write_h_outputs(ot, nws, b, s, x0, t, doAux, hxO, hxhO, hxlO, hwhO, part0);
}

// ---------------------------------------------------------------- head: gelu(fc1) -> fc2
__global__ __launch_bounds__(256) void k_head(
    const float* __restrict__ h, const float* __restrict__ W1,
    const float* __restrict__ b1, const float* __restrict__ W2,
    const float* __restrict__ b2, float* __restrict__ out){
    int bid = blockIdx.x;              // B * 250
    int b = bid / 250, n0 = (bid % 250) * 64;
    int t = threadIdx.x, w = t >> 6, f = t & 63;
    __shared__ float Wl[128][65];
    #pragma unroll
    for (int r = 0; r < 8; r++){
        int u = r*256 + t;
        int ff = u >> 4, cq = u & 15;
        float4 v = *(const float4*)&W1[ff*64 + cq*4];
        Wl[ff][cq*4+0] = v.x; Wl[ff][cq*4+1] = v.y;
        Wl[ff][cq*4+2] = v.z; Wl[ff][cq*4+3] = v.w;
    }
    __syncthreads();
    float w2a = W2[f], w2b = W2[64+f];
    float b1a = b1[f], b1b = b1[64+f];
    float b2v = b2[0];
    for (int g = 0; g < 16; g++){
        int n = n0 + w*16 + g;
        float hv = h[((size_t)b*NN + n)*CC + f];
        float a1 = b1a, a2 = b1b;
        #pragma unroll
        for (int c2 = 0; c2 < 64; c2++){
            float xv = __shfl(hv, c2, 64);
            a1 += Wl[f][c2] * xv;
            a2 += Wl[64+f][c2] * xv;
        }
        float p = gelu_f(a1)*w2a + gelu_f(a2)*w2b;
        for (int off = 32; off; off >>= 1) p += __shfl_down(p, off, 64);
        if (f == 0) out[(size_t)b*NN + n] = p + b2v;
    }
}

// ---------------------------------------------------------------- host
extern "C" void kernel_launch(void* const* d_in, const int* in_sizes, int n_in,
                              void* d_out, int out_size, void* d_ws, size_t ws_size,
                              hipStream_t stream){
    const float* x_in  = (const float*)d_in[0];
    const float* nodes = (const float*)d_in[2];
    const float* nw    = (const float*)d_in[3];
    const int*   edges = (const int*)d_in[4];
    const float* egw   = (const float*)d_in[5];
    const float* modes = (const float*)d_in[6];
    const float* latent= (const float*)d_in[7];
    const float* fc0W  = (const float*)d_in[8];
    const float* fc0b  = (const float*)d_in[9];
    const float* wc    = (const float*)d_in[10];
    const float* wsp   = (const float*)d_in[11];
    const float* w0    = (const float*)d_in[12];
    const float* wsW   = (const float*)d_in[13];
    const float* wsb   = (const float*)d_in[14];
    const float* gwsW  = (const float*)d_in[15];
    const float* gwsb  = (const float*)d_in[16];
    const float* fc1W  = (const float*)d_in[17];
    const float* fc1b  = (const float*)d_in[18];
    const float* fc2W  = (const float*)d_in[19];
    const float* fc2b  = (const float*)d_in[20];
    float* out = (float*)d_out;

    char* wsbase = (char*)d_ws;
    size_t off = 0;
    auto alloc = [&](size_t bytes) -> void* {
        void* p = wsbase + off;
        off += (bytes + 255) & ~(size_t)255;
        return p;
    };
    ushort* cbh = (ushort*)alloc((size_t)BB*NN*128*2);
    ushort* sbh = (ushort*)alloc((size_t)BB*NN*128*2);
    ushort* wTh = (ushort*)alloc((size_t)BB*256*NN*2);
    float*  hx[2];  ushort* hxh[2]; ushort* hxl[2]; ushort* hwh[2];
    for (int i = 0; i < 2; i++){
        hx[i]  = (float*) alloc((size_t)BB*NN*64*4);
        hxh[i] = (ushort*)alloc((size_t)BB*NN*64*2);
        hxl[i] = (ushort*)alloc((size_t)BB*NN*64*2);
        hwh[i] = (ushort*)alloc((size_t)BB*64*NN*2);
    }
    ushort* segh = (ushort*)alloc((size_t)BB*NN*128*2);
    ushort* segl = (ushort*)alloc((size_t)BB*NN*128*2);
    float*  part = (float*) alloc((size_t)BB*250*64*256*4);
    float*  part0= (float*) alloc((size_t)BB*125*4*64*4);
    float*  Sc   = (float*) alloc((size_t)BB*64*128*4);
    float*  Ss   = (float*) alloc((size_t)BB*64*128*4);
    ushort* WbH  = (ushort*)alloc((size_t)BB*64*448*2);
    ushort* WbL  = (ushort*)alloc((size_t)BB*64*448*2);
    float*  bias = (float*) alloc((size_t)BB*64*4);
    int*   cnt   = (int*)   alloc((size_t)BB*NN*4);
    int*   rowptr= (int*)   alloc((size_t)BB*(NN+4)*4);
    int*   cursor= (int*)   alloc((size_t)BB*NN*4);
    int*   insrc = (int*)   alloc((size_t)BB*EE*4);
    float2* inw  = (float2*)alloc((size_t)BB*EE*8);

    k_bases<<<BB*250, 256, 0, stream>>>(nodes, modes, latent, cbh, sbh, wTh);
    k_fc0<<<BB*125, 256, 0, stream>>>(x_in, fc0W, fc0b, nw,
                                      hx[0], hxh[0], hxl[0], hwh[0], part0);

    hipMemsetAsync(cnt, 0, (size_t)BB*NN*4, stream);
    csr_hist<<<(BB*EE+255)/256, 256, 0, stream>>>(edges, cnt);
    csr_scan<<<BB, 1024, 0, stream>>>(cnt, rowptr, cursor);
    csr_fill<<<(BB*EE+255)/256, 256, 0, stream>>>(edges, egw, cursor, insrc, inw);

    int cur = 0;
    for (int l = 0; l < LL; l++){
        int nxt = cur ^ 1;
        int doAux = (l < LL-1) ? 1 : 0;
        k1_fwd<<<BB*250, 256, 0, stream>>>(hwh[cur], wTh, part);
        k1_reduce<<<BB*128, 256, 0, stream>>>(part, Sc, Ss);
        k2_mix<<<BB*64, 256, 0, stream>>>(Sc, Ss, part0, wc, wsp, w0, wsb, gwsb,
                                          wsW, gwsW, WbH, WbL, bias, l);
        k_grad<<<BB*2000, 256, 0, stream>>>(hx[cur], rowptr, insrc, inw, segh, segl);
        k3_gemm<<<BB*125, 256, 0, stream>>>(WbH, WbL, bias,
                                            cbh, sbh,
                                            hxh[cur], hxl[cur], segh, segl, nw,
                                            hx[nxt], hxh[nxt], hxl[nxt],
                                            hwh[nxt], part0, doAux);
        cur = nxt;
    }
    k_head<<<BB*250, 256, 0, stream>>>(hx[cur], fc1W, fc1b, fc2W, fc2b, out);
    (void)in_sizes; (void)n_in; (void)out_size; (void)ws_size;
}

// Round 7
// 527.292 us; speedup vs baseline: 1.0974x; 1.0486x over previous
//
#include <hip/hip_runtime.h>
#include <math.h>

#define BB 2
#define NN 16000
#define EE 160000
#define KK 128
#define CC 64
#define LL 3

typedef __attribute__((ext_vector_type(8))) short bf16x8;
typedef __attribute__((ext_vector_type(4))) float f32x4;

__device__ __forceinline__ float gelu_f(float x){
    float x3 = x * x * x;
    return 0.5f * x * (1.f + tanhf(0.7978845608028654f * (x + 0.044715f * x3)));
}
__device__ __forceinline__ ushort f2bf(float f){
    uint u = __float_as_uint(f);
    u += 0x7fff + ((u >> 16) & 1);
    return (ushort)(u >> 16);
}
__device__ __forceinline__ float bf2f(ushort h){ return __uint_as_float(((uint)h) << 16); }
__device__ __forceinline__ void fsplit(float v, ushort &hi, ushort &lo){
    hi = f2bf(v);
    lo = f2bf(v - bf2f(hi));
}
__device__ __forceinline__ uint pk2(ushort a, ushort b){ return (uint)a | ((uint)b << 16); }

// ---------------------------------------------------------------- shared epilogue
__device__ __forceinline__ void write_h_outputs(
    const float* ot, const float* nws, int b, int s, int x0, int t, int doAux,
    float* __restrict__ hx, ushort* __restrict__ hxh, ushort* __restrict__ hxl,
    ushort* __restrict__ hwh, float* __restrict__ part0){
    {
        int xl = t >> 1, half = t & 1;
        size_t gb = ((size_t)b*NN + x0 + xl)*64 + half*32;
        const float* row = &ot[xl*68 + half*32];
        #pragma unroll
        for (int j = 0; j < 8; j++){
            float4 v; v.x = row[j*4]; v.y = row[j*4+1]; v.z = row[j*4+2]; v.w = row[j*4+3];
            *(float4*)&hx[gb + j*4] = v;
        }
        if (doAux){
            #pragma unroll
            for (int q = 0; q < 4; q++){
                ushort h_[8], l_[8];
                #pragma unroll
                for (int j = 0; j < 8; j++) fsplit(row[q*8 + j], h_[j], l_[j]);
                uint4 vh, vl;
                vh.x = pk2(h_[0],h_[1]); vh.y = pk2(h_[2],h_[3]); vh.z = pk2(h_[4],h_[5]); vh.w = pk2(h_[6],h_[7]);
                vl.x = pk2(l_[0],l_[1]); vl.y = pk2(l_[2],l_[3]); vl.z = pk2(l_[4],l_[5]); vl.w = pk2(l_[6],l_[7]);
                *(uint4*)&hxh[gb + q*8] = vh;
                *(uint4*)&hxl[gb + q*8] = vl;
            }
        }
    }
    if (doAux){
        int i = t & 63, g = t >> 6;
        float a = 0.f;
        #pragma unroll
        for (int rep = 0; rep < 4; rep++){
            int xs = g*32 + rep*8;
            ushort h_[8];
            #pragma unroll
            for (int j = 0; j < 8; j++){
                float v = ot[(xs + j)*68 + i] * nws[xs + j];
                a += v;
                h_[j] = f2bf(v);
            }
            uint4 vh;
            vh.x = pk2(h_[0],h_[1]); vh.y = pk2(h_[2],h_[3]); vh.z = pk2(h_[4],h_[5]); vh.w = pk2(h_[6],h_[7]);
            size_t wb = (size_t)(b*64 + i)*16000 + x0 + xs;
            *(uint4*)&hwh[wb] = vh;
        }
        part0[((size_t)(b*125 + s)*4 + g)*64 + i] = a;
    }
}

// ---------------------------------------------------------------- roles for merged start kernel
__device__ void bases_role(
    int bid, char* smem,
    const float* __restrict__ nodes, const float* __restrict__ modes,
    const float* __restrict__ latent,
    ushort* __restrict__ cbh, ushort* __restrict__ sbh,
    ushort* __restrict__ wTh){
    int b = bid / 250, x0 = (bid % 250) * 64;
    int t = threadIdx.x;
    float* sm0 = (float*)smem;          // 128
    float* sm1 = sm0 + 128;             // 128
    uint* tc = (uint*)(sm1 + 128);      // 64*65
    uint* ts = tc + 64*65;              // 64*65
    if (t < 128){
        float i0 = 0.5f + 1.5f / (1.f + expf(-latent[0]));
        float i1 = 0.5f + 1.5f / (1.f + expf(-latent[1]));
        sm0[t] = modes[t*2+0] * i0;
        sm1[t] = modes[t*2+1] * i1;
    }
    __syncthreads();
    int xloc = t & 63;
    float n0 = nodes[((size_t)b*NN + x0 + xloc)*2 + 0];
    float n1 = nodes[((size_t)b*NN + x0 + xloc)*2 + 1];
    for (int kh = 0; kh < 2; kh++){
        int kq = t >> 6;
        #pragma unroll
        for (int j = 0; j < 16; j++){
            int kl = kq*16 + j;
            int k = kh*64 + kl;
            float tmp = n0*sm0[k] + n1*sm1[k];
            float sv, cv; sincosf(tmp, &sv, &cv);
            tc[xloc*65 + kl] = (uint)f2bf(cv);
            ts[xloc*65 + kl] = (uint)f2bf(sv);
        }
        __syncthreads();
        {   // cb/sb x-major hi
            int q = t >> 6;
            size_t base = ((size_t)b*NN + x0 + xloc)*128 + kh*64 + q*16;
            #pragma unroll
            for (int g2 = 0; g2 < 2; g2++){
                uint u0 = tc[xloc*65 + q*16 + g2*8 + 0], u1 = tc[xloc*65 + q*16 + g2*8 + 1];
                uint u2 = tc[xloc*65 + q*16 + g2*8 + 2], u3 = tc[xloc*65 + q*16 + g2*8 + 3];
                uint u4 = tc[xloc*65 + q*16 + g2*8 + 4], u5 = tc[xloc*65 + q*16 + g2*8 + 5];
                uint u6 = tc[xloc*65 + q*16 + g2*8 + 6], u7 = tc[xloc*65 + q*16 + g2*8 + 7];
                uint4 vh;
                vh.x = pk2((ushort)u0,(ushort)u1); vh.y = pk2((ushort)u2,(ushort)u3);
                vh.z = pk2((ushort)u4,(ushort)u5); vh.w = pk2((ushort)u6,(ushort)u7);
                *(uint4*)&cbh[base + g2*8] = vh;
                u0 = ts[xloc*65 + q*16 + g2*8 + 0]; u1 = ts[xloc*65 + q*16 + g2*8 + 1];
                u2 = ts[xloc*65 + q*16 + g2*8 + 2]; u3 = ts[xloc*65 + q*16 + g2*8 + 3];
                u4 = ts[xloc*65 + q*16 + g2*8 + 4]; u5 = ts[xloc*65 + q*16 + g2*8 + 5];
                u6 = ts[xloc*65 + q*16 + g2*8 + 6]; u7 = ts[xloc*65 + q*16 + g2*8 + 7];
                vh.x = pk2((ushort)u0,(ushort)u1); vh.y = pk2((ushort)u2,(ushort)u3);
                vh.z = pk2((ushort)u4,(ushort)u5); vh.w = pk2((ushort)u6,(ushort)u7);
                *(uint4*)&sbh[base + g2*8] = vh;
            }
        }
        {   // wT k-major UNWEIGHTED hi
            int k = t & 63, g = t >> 6;
            int kgc = kh*64 + k;
            int kgs = 128 + kh*64 + k;
            ushort hc[16], hs[16];
            #pragma unroll
            for (int j = 0; j < 16; j++){
                int xx = g*16 + j;
                hc[j] = (ushort)tc[xx*65 + k];
                hs[j] = (ushort)ts[xx*65 + k];
            }
            size_t wbc = ((size_t)b*256 + kgc)*16000 + x0 + g*16;
            size_t wbs = ((size_t)b*256 + kgs)*16000 + x0 + g*16;
            uint4 v;
            v.x = pk2(hc[0],hc[1]); v.y = pk2(hc[2],hc[3]); v.z = pk2(hc[4],hc[5]); v.w = pk2(hc[6],hc[7]);
            *(uint4*)&wTh[wbc] = v;
            v.x = pk2(hc[8],hc[9]); v.y = pk2(hc[10],hc[11]); v.z = pk2(hc[12],hc[13]); v.w = pk2(hc[14],hc[15]);
            *(uint4*)&wTh[wbc + 8] = v;
            v.x = pk2(hs[0],hs[1]); v.y = pk2(hs[2],hs[3]); v.z = pk2(hs[4],hs[5]); v.w = pk2(hs[6],hs[7]);
            *(uint4*)&wTh[wbs] = v;
            v.x = pk2(hs[8],hs[9]); v.y = pk2(hs[10],hs[11]); v.z = pk2(hs[12],hs[13]); v.w = pk2(hs[14],hs[15]);
            *(uint4*)&wTh[wbs + 8] = v;
        }
        __syncthreads();
    }
}

__device__ void fc0_role(
    int bid, char* smem,
    const float* __restrict__ x, const float* __restrict__ W,
    const float* __restrict__ bb, const float* __restrict__ nw,
    float* __restrict__ hx, ushort* __restrict__ hxh, ushort* __restrict__ hxl,
    ushort* __restrict__ hwh, float* __restrict__ part0){
    int b = bid / 125, s = bid % 125;
    int x0 = s * 128;
    int t = threadIdx.x;
    float* ot  = (float*)smem;      // 128*68
    float* nws = ot + 128*68;       // 128
    float* Wf  = nws + 128;         // 192
    float* bf_ = Wf + 192;          // 64
    if (t < 192) Wf[t] = W[t];
    if (t < 64) bf_[t] = bb[t];
    if (t < 128) nws[t] = nw[b*NN + x0 + t];
    __syncthreads();
    {
        int xl = t >> 1, half = t & 1;
        float v0 = x[((size_t)b*NN + x0 + xl)*3 + 0];
        float v1 = x[((size_t)b*NN + x0 + xl)*3 + 1];
        float v2 = x[((size_t)b*NN + x0 + xl)*3 + 2];
        #pragma unroll
        for (int j = 0; j < 32; j++){
            int o = half*32 + j;
            ot[xl*68 + o] = Wf[o*3]*v0 + Wf[o*3+1]*v1 + Wf[o*3+2]*v2 + bf_[o];
        }
    }
    __syncthreads();
    write_h_outputs(ot, nws, b, s, x0, t, 1, hx, hxh, hxl, hwh, part0);
}

// S1: bases (500) | fc0 (250) | zero-cnt (125)
__global__ __launch_bounds__(256) void k_start(
    const float* __restrict__ nodes, const float* __restrict__ modes,
    const float* __restrict__ latent, const float* __restrict__ nw,
    const float* __restrict__ x, const float* __restrict__ fc0W,
    const float* __restrict__ fc0b,
    ushort* __restrict__ cbh, ushort* __restrict__ sbh, ushort* __restrict__ wTh,
    float* __restrict__ hx, ushort* __restrict__ hxh, ushort* __restrict__ hxl,
    ushort* __restrict__ hwh, float* __restrict__ part0,
    int* __restrict__ cnt){
    __shared__ __align__(16) char smem[36864];
    int bid = blockIdx.x;
    if (bid < BB*250){
        bases_role(bid, smem, nodes, modes, latent, cbh, sbh, wTh);
    } else if (bid < BB*250 + BB*125){
        fc0_role(bid - BB*250, smem, x, fc0W, fc0b, nw, hx, hxh, hxl, hwh, part0);
    } else {
        int idx = (bid - (BB*250 + BB*125))*256 + threadIdx.x;   // 125*256 == BB*NN
        cnt[idx] = 0;
    }
}

// ---------------------------------------------------------------- CSR build
__global__ __launch_bounds__(256) void csr_hist(
    const int* __restrict__ edges, int* __restrict__ cnt){
    int idx = blockIdx.x * 256 + threadIdx.x;
    if (idx >= BB*EE) return;
    int b = idx / EE;
    int tgt = edges[(size_t)idx*2];
    atomicAdd(&cnt[b*NN + tgt], 1);
}

__global__ __launch_bounds__(1024) void csr_scan(
    const int* __restrict__ cnt, int* __restrict__ rowptr, int* __restrict__ cursor){
    int b = blockIdx.x;
    int t = threadIdx.x;
    __shared__ int lds[1024];
    int base = t * 16;
    int v[16];
    int run = 0;
    #pragma unroll
    for (int j = 0; j < 16; j++){
        int n = base + j;
        int c = (n < NN) ? cnt[b*NN + n] : 0;
        v[j] = run;
        run += c;
    }
    lds[t] = run;
    __syncthreads();
    for (int off = 1; off < 1024; off <<= 1){
        int xv = (t >= off) ? lds[t-off] : 0;
        __syncthreads();
        lds[t] += xv;
        __syncthreads();
    }
    int toff = lds[t] - run;  // exclusive
    #pragma unroll
    for (int j = 0; j < 16; j++){
        int n = base + j;
        if (n < NN){
            int p = toff + v[j];
            rowptr[b*(NN+1) + n] = p;
            cursor[b*NN + n] = p;
        }
    }
    if (t == 1023) rowptr[b*(NN+1) + NN] = lds[1023];
}

__global__ __launch_bounds__(256) void csr_fill(
    const int* __restrict__ edges, const float* __restrict__ egw,
    int* __restrict__ cursor, int* __restrict__ insrc, float2* __restrict__ inw){
    int idx = blockIdx.x * 256 + threadIdx.x;
    if (idx >= BB*EE) return;
    int b = idx / EE;
    int tgt = edges[(size_t)idx*2];
    int src = edges[(size_t)idx*2 + 1];
    int pos = atomicAdd(&cursor[b*NN + tgt], 1);
    insrc[(size_t)b*EE + pos] = src;
    const float2 wv = *(const float2*)&egw[(size_t)idx*2];
    inw[(size_t)b*EE + pos] = wv;
}

// ---------------------------------------------------------------- forward transform: pure-bf16 MFMA, packed bf16 partials
// partu[(b*250+s)*64 + i][j(128)] : uint = (bf16 cos_j | bf16 sin_j), j = k%128
__global__ __launch_bounds__(256) void k1_fwd(
    const ushort* __restrict__ hwH,
    const ushort* __restrict__ wTH,
    uint* __restrict__ partu){
    int bid = blockIdx.x;              // B*250
    int b = bid / 250, s = bid % 250;
    int x0 = s * 64;
    int t = threadIdx.x, l = t & 63, w = t >> 6;
    __shared__ __align__(16) ushort Bh[128*64];
    f32x4 acc[16] = {};
    bf16x8 Ah[2];
    int i = w*16 + (l & 15);
    #pragma unroll
    for (int ks = 0; ks < 2; ks++){
        size_t ab = (size_t)(b*64 + i)*16000 + x0 + ks*32 + ((l >> 4) * 8);
        Ah[ks] = *reinterpret_cast<const bf16x8*>(&hwH[ab]);
    }
    for (int p = 0; p < 2; p++){
        if (p) __syncthreads();
        #pragma unroll
        for (int it = 0; it < 4; it++){
            int u = it*256 + t;
            int kloc = u >> 3, q = u & 7;
            size_t g = ((size_t)(b*256 + p*128 + kloc))*16000 + x0 + q*8;
            uint4 vh = *(const uint4*)&wTH[g];
            int ldsb = kloc*128 + ((q*16) ^ ((kloc & 7) << 4));
            *(uint4*)&Bh[ldsb >> 1] = vh;
        }
        __syncthreads();
        #pragma unroll
        for (int kt = 0; kt < 8; kt++){
            int kcol = kt*16 + (l & 15);
            int ai = p*8 + kt;
            #pragma unroll
            for (int ks = 0; ks < 2; ks++){
                int boff = kcol*128 + (((ks*64) + ((l >> 4) * 16)) ^ ((kcol & 7) << 4));
                bf16x8 bh = *reinterpret_cast<const bf16x8*>(&Bh[boff >> 1]);
                acc[ai] = __builtin_amdgcn_mfma_f32_16x16x32_bf16(Ah[ks], bh, acc[ai], 0, 0, 0);
            }
        }
    }
    size_t pb = (size_t)(b*250 + s) * 64 * 128;
    #pragma unroll
    for (int nt = 0; nt < 8; nt++){
        #pragma unroll
        for (int r = 0; r < 4; r++){
            int irow = w*16 + (l >> 4)*4 + r;
            partu[pb + (size_t)irow*128 + nt*16 + (l & 15)] =
                pk2(f2bf(acc[nt][r]), f2bf(acc[nt+8][r]));
        }
    }
}

// ---------------------------------------------------------------- partial reduce (packed bf16 -> Sc/Ss f32)
__global__ __launch_bounds__(512) void k1_reduce(
    const uint* __restrict__ partu, float* __restrict__ Sc, float* __restrict__ Ss){
    int b = blockIdx.x >> 6, i = blockIdx.x & 63;   // grid B*64
    int t = threadIdx.x;
    int j = t & 127, sh = t >> 7;                   // 4 s-groups
    const uint* pb = partu + ((size_t)(b*250)*64 + i)*128 + j;
    float c0=0,c1=0,s0a=0,s1a=0;
    int s2 = sh;
    for (; s2 + 4 < 250; s2 += 8){
        uint v0 = pb[(size_t)s2*8192];
        uint v1 = pb[(size_t)(s2+4)*8192];
        c0 += bf2f((ushort)v0); s0a += bf2f((ushort)(v0 >> 16));
        c1 += bf2f((ushort)v1); s1a += bf2f((ushort)(v1 >> 16));
    }
    for (; s2 < 250; s2 += 4){
        uint v0 = pb[(size_t)s2*8192];
        c0 += bf2f((ushort)v0); s0a += bf2f((ushort)(v0 >> 16));
    }
    float cs = c0 + c1, ss = s0a + s1a;
    __shared__ float rC[4][128], rS[4][128];
    rC[sh][j] = cs; rS[sh][j] = ss;
    __syncthreads();
    if (sh == 0){
        cs = rC[0][j] + rC[1][j] + rC[2][j] + rC[3][j];
        ss = rS[0][j] + rS[1][j] + rS[2][j] + rS[3][j];
        Sc[(size_t)(b*64 + i)*128 + j] = cs;
        Ss[(size_t)(b*64 + i)*128 + j] = ss;
    }
}

// ---------------------------------------------------------------- per-mode channel mix -> Wbig(hi/lo), bias
__global__ __launch_bounds__(256) void k2_mix(
    const float* __restrict__ Sc, const float* __restrict__ Ss,
    const float* __restrict__ part0,
    const float* __restrict__ wc, const float* __restrict__ wsp,
    const float* __restrict__ w0,
    const float* __restrict__ wsb, const float* __restrict__ gwsb,
    const float* __restrict__ wsW, const float* __restrict__ gwsW,
    ushort* __restrict__ WbH, ushort* __restrict__ WbL,
    float* __restrict__ bias, int l){
    int b = blockIdx.x >> 6, o = blockIdx.x & 63;
    int t = threadIdx.x;
    __shared__ float fc2s[2][128], fs2s[2][128];
    __shared__ float redp[4][64];
    __shared__ float red[64];
    {   // parallel part0 reduction (500 slices)
        int i = t & 63, grp = t >> 6;
        float a = 0.f;
        for (int s2 = grp; s2 < 500; s2 += 4)
            a += part0[(size_t)(b*500 + s2)*64 + i];
        redp[grp][i] = a;
    }
    int k = t & 127, hf = t >> 7;
    float fc = 0.f, fs = 0.f;
    for (int i = hf*32; i < hf*32 + 32; i++){
        float sc = Sc[(size_t)(b*CC + i)*KK + k];
        float ss = Ss[(size_t)(b*CC + i)*KK + k];
        size_t wi = (((size_t)l*CC + i)*CC + o)*KK + k;
        float a = wc[wi], bb2 = wsp[wi];
        fc += sc*a + ss*bb2;
        fs += sc*bb2 - ss*a;
    }
    fc2s[hf][k] = fc; fs2s[hf][k] = fs;
    __syncthreads();
    if (t < 64)
        red[t] = (redp[0][t]+redp[1][t]+redp[2][t]+redp[3][t]) * w0[((size_t)l*CC + t)*CC + o];
    size_t wb = (size_t)(b*CC + o) * 448;
    if (t < 128){
        float FC = fc2s[0][t] + fc2s[1][t];
        float FS = fs2s[0][t] + fs2s[1][t];
        ushort h_, l_;
        fsplit(2.f*FC, h_, l_);
        WbH[wb + t] = h_; WbL[wb + t] = l_;
        fsplit(-2.f*FS, h_, l_);
        WbH[wb + 128 + t] = h_; WbL[wb + 128 + t] = l_;
    }
    if (t >= 128 && t < 192){
        int q = t - 128;  // wsW 0..63
        float v = wsW[((size_t)l*CC + o)*CC + q];
        ushort h_, l_; fsplit(v, h_, l_);
        WbH[wb + 256 + q] = h_; WbL[wb + 256 + q] = l_;
    }
    if (t >= 128){
        int q = t - 128;  // gwsW 0..127
        float v = gwsW[((size_t)l*CC + o)*128 + q];
        ushort h_, l_; fsplit(v, h_, l_);
        WbH[wb + 320 + q] = h_; WbL[wb + 320 + q] = l_;
    }
    __syncthreads();
    if (t == 0){
        float f0 = 0.f;
        for (int i = 0; i < 64; i++) f0 += red[i];
        bias[b*CC + o] = f0 + wsb[l*CC + o] + gwsb[l*CC + o];
    }
}

// ---------------------------------------------------------------- gradient field (CSR, atomic-free)
__global__ __launch_bounds__(256) void k_grad(
    const float* __restrict__ h, const int* __restrict__ rowptr,
    const int* __restrict__ insrc, const float2* __restrict__ inw,
    ushort* __restrict__ segh, ushort* __restrict__ segl){
    int bid = blockIdx.x;              // B * 2000
    int b = bid / 2000, n0 = (bid % 2000) * 8;
    int w = threadIdx.x >> 6, c = threadIdx.x & 63;
    const float*  hb  = h + (size_t)b*NN*CC;
    const int*    isb = insrc + (size_t)b*EE;
    const float2* iwb = inw + (size_t)b*EE;
    #pragma unroll
    for (int g = 0; g < 2; g++){
        int n = n0 + w*2 + g;
        float hn = hb[(size_t)n*CC + c];
        int p0 = rowptr[b*(NN+1) + n];
        int p1 = rowptr[b*(NN+1) + n + 1];
        float a0 = 0.f, a1 = 0.f;
        int p = p0;
        for (; p + 4 <= p1; p += 4){
            int s0 = isb[p], s1 = isb[p+1], s2 = isb[p+2], s3 = isb[p+3];
            float2 w0 = iwb[p], w1 = iwb[p+1], w2 = iwb[p+2], w3 = iwb[p+3];
            float d0 = hb[(size_t)s0*CC + c] - hn;
            float d1 = hb[(size_t)s1*CC + c] - hn;
            float d2 = hb[(size_t)s2*CC + c] - hn;
            float d3 = hb[(size_t)s3*CC + c] - hn;
            a0 += w0.x*d0 + w1.x*d1 + w2.x*d2 + w3.x*d3;
            a1 += w0.y*d0 + w1.y*d1 + w2.y*d2 + w3.y*d3;
        }
        for (; p < p1; p++){
            int sx = isb[p]; float2 ww = iwb[p];
            float d = hb[(size_t)sx*CC + c] - hn;
            a0 += ww.x*d; a1 += ww.y*d;
        }
        ushort h0_, l0_, h1_, l1_;
        fsplit(a0, h0_, l0_);
        fsplit(a1, h1_, l1_);
        size_t sb2 = ((size_t)b*NN + n)*128 + 2*c;
        *(uint*)&segh[sb2] = pk2(h0_, h1_);
        *(uint*)&segl[sb2] = pk2(l0_, l1_);
    }
}

// ---------------------------------------------------------------- layer output GEMM (tiered precision)
__global__ __launch_bounds__(256) void k3_gemm(
    const ushort* __restrict__ WbH, const ushort* __restrict__ WbL,
    const float* __restrict__ bias,
    const ushort* __restrict__ cbh, const ushort* __restrict__ sbh,
    const ushort* __restrict__ hxh, const ushort* __restrict__ hxl,
    const ushort* __restrict__ sgh, const ushort* __restrict__ sgl,
    const float* __restrict__ nw,
    float* __restrict__ hxO, ushort* __restrict__ hxhO, ushort* __restrict__ hxlO,
    ushort* __restrict__ hwhO, float* __restrict__ part0,
    int doAux){
    int bid = blockIdx.x;              // B*125
    int b = bid / 125, s = bid % 125, x0 = s * 128;
    int t = threadIdx.x, l = t & 63, w = t >> 6;
    __shared__ __align__(16) char smem[34816];
    ushort* Vh = (ushort*)smem;
    ushort* Vl = Vh + 8192;
    __shared__ float nws[128];
    if (t < 128) nws[t] = nw[b*NN + x0 + t];
    f32x4 acc[8] = {};
    int o = w*16 + (l & 15);
    for (int cc = 0; cc < 7; cc++){
        const ushort *srcH, *srcL; int rl, co, lo;
        switch (cc){
            case 0:  srcH = cbh; srcL = cbh; rl = 128; co = 0;  lo = 0; break;
            case 1:  srcH = cbh; srcL = cbh; rl = 128; co = 64; lo = 0; break;
            case 2:  srcH = sbh; srcL = sbh; rl = 128; co = 0;  lo = 0; break;
            case 3:  srcH = sbh; srcL = sbh; rl = 128; co = 64; lo = 0; break;
            case 4:  srcH = hxh; srcL = hxl; rl = 64;  co = 0;  lo = 1; break;
            case 5:  srcH = sgh; srcL = sgl; rl = 128; co = 0;  lo = 1; break;
            default: srcH = sgh; srcL = sgl; rl = 128; co = 64; lo = 1; break;
        }
        __syncthreads();
        #pragma unroll
        for (int it = 0; it < 4; it++){
            int u = it*256 + t;
            int xl2 = u >> 3, q = u & 7;
            size_t g = (size_t)(b*NN + x0 + xl2)*rl + co + q*8;
            uint4 vh = *(const uint4*)&srcH[g];
            int ldsb = xl2*128 + ((q*16) ^ ((xl2 & 7) << 4));
            *(uint4*)&Vh[ldsb >> 1] = vh;
            if (lo){
                uint4 vl2 = *(const uint4*)&srcL[g];
                *(uint4*)&Vl[ldsb >> 1] = vl2;
            }
        }
        __syncthreads();
        bf16x8 Ah[2], Al[2];
        #pragma unroll
        for (int ks = 0; ks < 2; ks++){
            size_t ab = (size_t)(b*64 + o)*448 + cc*64 + ks*32 + ((l >> 4) * 8);
            Ah[ks] = *reinterpret_cast<const bf16x8*>(&WbH[ab]);
            Al[ks] = *reinterpret_cast<const bf16x8*>(&WbL[ab]);
        }
        #pragma unroll
        for (int nt = 0; nt < 8; nt++){
            int xc = nt*16 + (l & 15);
            #pragma unroll
            for (int ks = 0; ks < 2; ks++){
                int boff = xc*128 + (((ks*64) + ((l >> 4) * 16)) ^ ((xc & 7) << 4));
                bf16x8 bh = *reinterpret_cast<const bf16x8*>(&Vh[boff >> 1]);
                acc[nt] = __builtin_amdgcn_mfma_f32_16x16x32_bf16(Ah[ks], bh, acc[nt], 0, 0, 0);
                if (lo){
                    bf16x8 bl = *reinterpret_cast<const bf16x8*>(&Vl[boff >> 1]);
                    acc[nt] = __builtin_amdgcn_mfma_f32_16x16x32_bf16(Ah[ks], bl, acc[nt], 0, 0, 0);
                    acc[nt] = __builtin_amdgcn_mfma_f32_16x16x32_bf16(Al[ks], bh, acc[nt], 0, 0, 0);
                }
            }
        }
    }
    __syncthreads();
    float* ot = (float*)smem;          // reuse as [128][68]
    float bv[4];
    #pragma unroll
    for (int r = 0; r < 4; r++) bv[r] = bias[b*64 + w*16 + (l >> 4)*4 + r];
    #pragma unroll
    for (int nt = 0; nt < 8; nt++){
        int xc = nt*16 + (l & 15);
        #pragma unroll
        for (int r = 0; r < 4; r++){
            float v = acc[nt][r] + bv[r];
            if (doAux) v = gelu_f(v);
            ot[xc*68 + (w*16 + (l >> 4)*4 + r)] = v;
        }
    }
    __syncthreads();
    write_h_outputs(ot, nws, b, s, x0, t, doAux, hxO, hxhO, hxlO, hwhO, part0);
}

// ---------------------------------------------------------------- head: gelu(fc1) -> fc2
__global__ __launch_bounds__(256) void k_head(
    const float* __restrict__ h, const float* __restrict__ W1,
    const float* __restrict__ b1, const float* __restrict__ W2,
    const float* __restrict__ b2, float* __restrict__ out){
    int bid = blockIdx.x;              // B * 250
    int b = bid / 250, n0 = (bid % 250) * 64;
    int t = threadIdx.x, w = t >> 6, f = t & 63;
    __shared__ float Wl[128][65];
    #pragma unroll
    for (int r = 0; r < 8; r++){
        int u = r*256 + t;
        int ff = u >> 4, cq = u & 15;
        float4 v = *(const float4*)&W1[ff*64 + cq*4];
        Wl[ff][cq*4+0] = v.x; Wl[ff][cq*4+1] = v.y;
        Wl[ff][cq*4+2] = v.z; Wl[ff][cq*4+3] = v.w;
    }
    __syncthreads();
    float w2a = W2[f], w2b = W2[64+f];
    float b1a = b1[f], b1b = b1[64+f];
    float b2v = b2[0];
    for (int g = 0; g < 16; g++){
        int n = n0 + w*16 + g;
        float hv = h[((size_t)b*NN + n)*CC + f];
        float a1 = b1a, a2 = b1b;
        #pragma unroll
        for (int c2 = 0; c2 < 64; c2++){
            float xv = __shfl(hv, c2, 64);
            a1 += Wl[f][c2] * xv;
            a2 += Wl[64+f][c2] * xv;
        }
        float p = gelu_f(a1)*w2a + gelu_f(a2)*w2b;
        for (int off = 32; off; off >>= 1) p += __shfl_down(p, off, 64);
        if (f == 0) out[(size_t)b*NN + n] = p + b2v;
    }
}

// ---------------------------------------------------------------- host
extern "C" void kernel_launch(void* const* d_in, const int* in_sizes, int n_in,
                              void* d_out, int out_size, void* d_ws, size_t ws_size,
                              hipStream_t stream){
    const float* x_in  = (const float*)d_in[0];
    const float* nodes = (const float*)d_in[2];
    const float* nw    = (const float*)d_in[3];
    const int*   edges = (const int*)d_in[4];
    const float* egw   = (const float*)d_in[5];
    const float* modes = (const float*)d_in[6];
    const float* latent= (const float*)d_in[7];
    const float* fc0W  = (const float*)d_in[8];
    const float* fc0b  = (const float*)d_in[9];
    const float* wc    = (const float*)d_in[10];
    const float* wsp   = (const float*)d_in[11];
    const float* w0    = (const float*)d_in[12];
    const float* wsW   = (const float*)d_in[13];
    const float* wsb   = (const float*)d_in[14];
    const float* gwsW  = (const float*)d_in[15];
    const float* gwsb  = (const float*)d_in[16];
    const float* fc1W  = (const float*)d_in[17];
    const float* fc1b  = (const float*)d_in[18];
    const float* fc2W  = (const float*)d_in[19];
    const float* fc2b  = (const float*)d_in[20];
    float* out = (float*)d_out;

    char* wsbase = (char*)d_ws;
    size_t off = 0;
    auto alloc = [&](size_t bytes) -> void* {
        void* p = wsbase + off;
        off += (bytes + 255) & ~(size_t)255;
        return p;
    };
    ushort* cbh = (ushort*)alloc((size_t)BB*NN*128*2);
    ushort* sbh = (ushort*)alloc((size_t)BB*NN*128*2);
    ushort* wTh = (ushort*)alloc((size_t)BB*256*NN*2);
    float*  hx[2];  ushort* hxh[2]; ushort* hxl[2]; ushort* hwh[2];
    for (int i = 0; i < 2; i++){
        hx[i]  = (float*) alloc((size_t)BB*NN*64*4);
        hxh[i] = (ushort*)alloc((size_t)BB*NN*64*2);
        hxl[i] = (ushort*)alloc((size_t)BB*NN*64*2);
        hwh[i] = (ushort*)alloc((size_t)BB*64*NN*2);
    }
    ushort* segh = (ushort*)alloc((size_t)BB*NN*128*2);
    ushort* segl = (ushort*)alloc((size_t)BB*NN*128*2);
    uint*   partu= (uint*)  alloc((size_t)BB*250*64*128*4);
    float*  part0= (float*) alloc((size_t)BB*125*4*64*4);
    float*  Sc   = (float*) alloc((size_t)BB*64*128*4);
    float*  Ss   = (float*) alloc((size_t)BB*64*128*4);
    ushort* WbH  = (ushort*)alloc((size_t)BB*64*448*2);
    ushort* WbL  = (ushort*)alloc((size_t)BB*64*448*2);
    float*  bias = (float*) alloc((size_t)BB*64*4);
    int*   cnt   = (int*)   alloc((size_t)BB*NN*4);
    int*   rowptr= (int*)   alloc((size_t)BB*(NN+4)*4);
    int*   cursor= (int*)   alloc((size_t)BB*NN*4);
    int*   insrc = (int*)   alloc((size_t)BB*EE*4);
    float2* inw  = (float2*)alloc((size_t)BB*EE*8);

    // S1: bases | fc0 | zero-cnt
    k_start<<<BB*250 + BB*125 + 125, 256, 0, stream>>>(
        nodes, modes, latent, nw, x_in, fc0W, fc0b,
        cbh, sbh, wTh,
        hx[0], hxh[0], hxl[0], hwh[0], part0, cnt);

    csr_hist<<<(BB*EE+255)/256, 256, 0, stream>>>(edges, cnt);
    csr_scan<<<BB, 1024, 0, stream>>>(cnt, rowptr, cursor);
    csr_fill<<<(BB*EE+255)/256, 256, 0, stream>>>(edges, egw, cursor, insrc, inw);

    int cur = 0;
    for (int l = 0; l < LL; l++){
        int nxt = cur ^ 1;
        int doAux = (l < LL-1) ? 1 : 0;
        k1_fwd<<<BB*250, 256, 0, stream>>>(hwh[cur], wTh, partu);
        k1_reduce<<<BB*64, 512, 0, stream>>>(partu, Sc, Ss);
        k2_mix<<<BB*64, 256, 0, stream>>>(Sc, Ss, part0, wc, wsp, w0, wsb, gwsb,
                                          wsW, gwsW, WbH, WbL, bias, l);
        k_grad<<<BB*2000, 256, 0, stream>>>(hx[cur], rowptr, insrc, inw, segh, segl);
        k3_gemm<<<BB*125, 256, 0, stream>>>(WbH, WbL, bias,
                                            cbh, sbh,
                                            hxh[cur], hxl[cur], segh, segl, nw,
                                            hx[nxt], hxh[nxt], hxl[nxt],
                                            hwh[nxt], part0, doAux);
        cur = nxt;
    }
    k_head<<<BB*250, 256, 0, stream>>>(hx[cur], fc1W, fc1b, fc2W, fc2b, out);
    (void)in_sizes; (void)n_in; (void)out_size; (void)ws_size;
}